// Round 18
// baseline (82.247 us; speedup 1.0000x reference)
//
#include <hip/hip_runtime.h>
#include <hip/hip_bf16.h>

#define BB 32
#define IDF 64
#define CDF 256
#define SSZ 1024
#define NH 8
#define LL 256
#define KHC 2048   // NH*CDF

typedef __attribute__((ext_vector_type(8))) _Float16 half8v;   // 8 fp16
typedef __attribute__((ext_vector_type(4))) float f32x4;       // MFMA acc

// async global->LDS, 16B per lane, LDS dest = wave-uniform base + lane*16
#define GLDS16(g, l) __builtin_amdgcn_global_load_lds(                        \
    (const __attribute__((address_space(1))) void*)(g),                       \
    (__attribute__((address_space(3))) void*)(l), 16, 0, 0)

// 3-deep pipeline phase entry (T3+T4): wait only for the CURRENT buffer's
// DMA, leaving the next TWO stages in flight. Never vmcnt(0) mid-loop.
#define WAIT_ENTER3(NFULL, NHALF)                                             \
  { if (ks < NSTEP - 2)                                                       \
      asm volatile("s_waitcnt vmcnt(" #NFULL ")" ::: "memory");               \
    else if (ks == NSTEP - 2)                                                 \
      asm volatile("s_waitcnt vmcnt(" #NHALF ")" ::: "memory");               \
    else                                                                      \
      asm volatile("s_waitcnt vmcnt(0)" ::: "memory");                        \
    __builtin_amdgcn_s_barrier();                                             \
    __builtin_amdgcn_sched_barrier(0); }
#define BAR_EXIT()                                                            \
  { __builtin_amdgcn_sched_barrier(0);                                        \
    __builtin_amdgcn_s_barrier();                                             \
    __builtin_amdgcn_sched_barrier(0); }
// LDS-only barrier: drains ds ops but leaves global_load_lds (vmcnt) in
// flight — lets phase-3 prefetch ride through the softmax.
#define LDS_BAR()                                                             \
  { asm volatile("s_waitcnt lgkmcnt(0)" ::: "memory");                        \
    __builtin_amdgcn_s_barrier();                                             \
    __builtin_amdgcn_sched_barrier(0); }

__device__ inline unsigned short f2h(float x) {
  _Float16 h = (_Float16)x;
  return *reinterpret_cast<unsigned short*>(&h);
}
__device__ inline float h2f(unsigned short u) {
  _Float16 h = *reinterpret_cast<_Float16*>(&u);
  return (float)h;
}

// ---------------------------------------------------------------------------
// Fused prep: blocks 0..6143 elementwise casts (wc,W,ctx -> fp16);
// blocks 6144..6655 -> Wt16 [h][c][o]; 6656..7167 -> cT16 [b][l][c].
// ---------------------------------------------------------------------------
__global__ __launch_bounds__(256) void k_prep(const float* __restrict__ wc,
                                              const float* __restrict__ W,
                                              const float* __restrict__ ctx,
                                              unsigned short* __restrict__ wc16,
                                              unsigned short* __restrict__ W16,
                                              unsigned short* __restrict__ ctx16,
                                              unsigned short* __restrict__ Wt16,
                                              unsigned short* __restrict__ cT16) {
  __shared__ float Tt[64][65];
  int blk0 = blockIdx.x;
  int t = threadIdx.x;
  if (blk0 < 6144) {                       // elementwise casts
    int sel = blk0 >> 11;
    int idx = ((blk0 & 2047) * 256 + t) * 4;
    const float* src = (sel == 0) ? wc : (sel == 1) ? W : ctx;
    unsigned short* d = (sel == 0) ? wc16 : (sel == 1) ? W16 : ctx16;
    float4 v = *reinterpret_cast<const float4*>(&src[idx]);
    __align__(8) unsigned short h[4] = {f2h(v.x), f2h(v.y), f2h(v.z), f2h(v.w)};
    *reinterpret_cast<int2*>(&d[idx]) = *reinterpret_cast<int2*>(h);
  } else if (blk0 < 6656) {                // W -> Wt16 [h][c][o]
    int blk = blk0 - 6144;
    int h = blk >> 6, ot = (blk >> 2) & 15, cq = blk & 3;
    int og = ot * 64, cg = cq * 64;
    int o_l = t >> 4, c4 = (t & 15) * 4;
#pragma unroll
    for (int p = 0; p < 4; ++p) {
      int o = o_l + 16 * p;
      float4 v = *reinterpret_cast<const float4*>(
          &W[((size_t)h * SSZ + og + o) * CDF + cg + c4]);
      Tt[c4 + 0][o] = v.x; Tt[c4 + 1][o] = v.y;
      Tt[c4 + 2][o] = v.z; Tt[c4 + 3][o] = v.w;
    }
    __syncthreads();
    int c_l = t >> 2;
#pragma unroll
    for (int p = 0; p < 4; ++p) {
      int o0 = ((t & 3) + 4 * p) * 4;
      __align__(8) unsigned short hv[4];
#pragma unroll
      for (int j = 0; j < 4; ++j) hv[j] = f2h(Tt[c_l][o0 + j]);
      size_t base = ((size_t)h * CDF + cg + c_l) * SSZ + og + o0;
      *reinterpret_cast<int2*>(&Wt16[base]) = *reinterpret_cast<int2*>(hv);
    }
  } else {                                 // ctx -> cT16 [b][l][c]
    int blk = blk0 - 6656;
    int b = blk >> 4, cq = (blk >> 2) & 3, lt = blk & 3;
    int cg = cq * 64, lg = lt * 64;
    int c_l = t >> 4, l4 = (t & 15) * 4;
#pragma unroll
    for (int p = 0; p < 4; ++p) {
      int c = c_l + 16 * p;
      float4 v = *reinterpret_cast<const float4*>(
          &ctx[((size_t)b * CDF + cg + c) * LL + lg + l4]);
      Tt[l4 + 0][c] = v.x; Tt[l4 + 1][c] = v.y;
      Tt[l4 + 2][c] = v.z; Tt[l4 + 3][c] = v.w;
    }
    __syncthreads();
    int l_l = t >> 2;
#pragma unroll
    for (int p = 0; p < 4; ++p) {
      int c0 = ((t & 3) + 4 * p) * 4;
      __align__(8) unsigned short hv[4];
#pragma unroll
      for (int j = 0; j < 4; ++j) hv[j] = f2h(Tt[l_l][c0 + j]);
      size_t base = ((size_t)b * LL + lg + l_l) * CDF + cg + c0;
      *reinterpret_cast<int2*>(&cT16[base]) = *reinterpret_cast<int2*>(hv);
    }
  }
}

// ---------------------------------------------------------------------------
// K1 (standalone, round-16 proven): M16 = wc*Wt^T. grid 512 = 2 blocks/CU:
// independent 4-wave barrier domains overlap across blocks (m114 mechanism
// the 8-wave fused k123 lost). 4 waves x (64i x 32c). BK=32, 32 steps.
// ---------------------------------------------------------------------------
__device__ __forceinline__ void k1_stage(short* dst,
                                         const short* gA, const short* gB,
                                         int wave, int lane, int k0) {
#pragma unroll
  for (int j = 0; j < 3; ++j) {
    int inst = wave * 3 + j;               // 0..11
    if (inst < 4) {
      int rb = inst * 16;
      int r  = rb + (lane >> 2);
      int gc = (lane & 3) ^ ((r >> 1) & 3);
      GLDS16(gA + (size_t)r * SSZ + k0 + gc * 8, dst + rb * 32);
    } else {
      int rb = (inst - 4) * 16;
      int r  = rb + (lane >> 2);
      int gc = (lane & 3) ^ ((r >> 1) & 3);
      GLDS16(gB + (size_t)r * SSZ + k0 + gc * 8, dst + 2048 + rb * 32);
    }
  }
}

__global__ __launch_bounds__(256) void k1_mfma(const unsigned short* __restrict__ wc16,
                                               const unsigned short* __restrict__ Wt16,
                                               unsigned short* __restrict__ M16) {
  __shared__ __align__(16) short S[3 * 6144];   // 36 KB

  int blk = blockIdx.x;
  int bh = blk >> 1, nh = blk & 1;
  int b = bh >> 3, h = bh & 7;
  int t = threadIdx.x;
  int lane = t & 63, wave = t >> 6;
  int ln15 = lane & 15, kh = lane >> 4;

  const short* gA = (const short*)wc16 + (size_t)b * IDF * SSZ;
  const short* gB = (const short*)Wt16 + (size_t)(h * CDF + nh * 128) * SSZ;

  int offA[4], offB[2];
#pragma unroll
  for (int r = 0; r < 4; ++r) {
    int row = r * 16 + ln15;
    offA[r] = row * 32 + ((kh ^ ((row >> 1) & 3)) * 8);
  }
#pragma unroll
  for (int c = 0; c < 2; ++c) {
    int row = wave * 32 + c * 16 + ln15;
    offB[c] = 2048 + row * 32 + ((kh ^ ((row >> 1) & 3)) * 8);
  }

  f32x4 acc[4][2] = {};
  k1_stage(&S[0],        gA, gB, wave, lane, 0);
  k1_stage(&S[6144],     gA, gB, wave, lane, 32);
  k1_stage(&S[2 * 6144], gA, gB, wave, lane, 64);
  int cur = 0;

  const int NSTEP = 32;
#pragma unroll 1
  for (int ks = 0; ks < NSTEP; ++ks) {
    short* Sc = &S[cur * 6144];
    WAIT_ENTER3(6, 3)
    half8v fa[4], fb[2];
#pragma unroll
    for (int r = 0; r < 4; ++r)
      fa[r] = *reinterpret_cast<const half8v*>(&Sc[offA[r]]);
#pragma unroll
    for (int c = 0; c < 2; ++c)
      fb[c] = *reinterpret_cast<const half8v*>(&Sc[offB[c]]);
    __builtin_amdgcn_s_setprio(1);
#pragma unroll
    for (int r = 0; r < 4; ++r)
#pragma unroll
      for (int c = 0; c < 2; ++c)
        acc[r][c] = __builtin_amdgcn_mfma_f32_16x16x32_f16(fa[r], fb[c], acc[r][c], 0, 0, 0);
    __builtin_amdgcn_s_setprio(0);
    BAR_EXIT()
    if (ks + 3 < NSTEP)
      k1_stage(Sc, gA, gB, wave, lane, (ks + 3) * 32);
    cur = (cur == 2) ? 0 : cur + 1;
  }

  size_t obase = (size_t)bh * IDF * CDF + nh * 128;
  int rowq = (lane >> 4) * 4;
#pragma unroll
  for (int r = 0; r < 4; ++r)
#pragma unroll
    for (int c = 0; c < 2; ++c)
#pragma unroll
      for (int reg = 0; reg < 4; ++reg) {
        size_t idx = obase + (size_t)(r * 16 + rowq + reg) * CDF + wave * 32 + c * 16 + ln15;
        M16[idx] = f2h(acc[r][c][reg]);
      }
}

// ---------------------------------------------------------------------------
// k23: fused K2+K3 per bh. grid 256, 512 thr = 8 waves x (64i x 32col).
// Phase 2: logits = M16 x cT^T (K=256, 8 steps, A+B+dup staged, 3/wave)
//          -> softmax -> P (global + P_lds)
// Phase 3: N2 = P_lds x ctx^T (K=256, 8 steps, B staged 2/wave)
// Phase-3 B prefetched BEFORE softmax; softmax uses lgkm-only barriers.
// LDS: staging 3x24KB + P_lds 32KB = 104 KB (grid=256 -> 1 block/CU anyway).
// ---------------------------------------------------------------------------
__device__ __forceinline__ void st_p2(short* dst, const short* gM, const short* gT,
                                      int wave, int lane, int k0) {
#pragma unroll
  for (int j = 0; j < 3; ++j) {
    int inst = wave * 3 + j;               // 0..23
    const short* src; int toff, rb;
    if (inst < 4)       { src = gM; toff = 0;     rb = inst * 16; }
    else if (inst < 20) { src = gT; toff = 2048;  rb = (inst - 4) * 16; }
    else                { src = gM; toff = 10240; rb = (inst - 20) * 16; } // dup
    int r  = rb + (lane >> 2);
    int gc = (lane & 3) ^ ((r >> 1) & 3);
    GLDS16(src + (size_t)r * CDF + k0 + gc * 8, dst + toff + rb * 32);
  }
}
__device__ __forceinline__ void st_pB(short* dst, const short* gB, int ld,
                                      int wave, int lane, int k0) {
#pragma unroll
  for (int j = 0; j < 2; ++j) {
    int inst = wave * 2 + j;               // 0..15
    int rb = inst * 16;
    int r  = rb + (lane >> 2);
    int gc = (lane & 3) ^ ((r >> 1) & 3);
    GLDS16(gB + (size_t)r * ld + k0 + gc * 8, dst + 2048 + rb * 32);
  }
}

__global__ __launch_bounds__(512) void k23(const unsigned short* __restrict__ M16,
                                           const unsigned short* __restrict__ cT16,
                                           const unsigned short* __restrict__ ctx16,
                                           unsigned short* __restrict__ P16,
                                           unsigned short* __restrict__ N216) {
  __shared__ __align__(16) short S[3 * 12288 + 16384];   // 104 KB
  short* P_lds = &S[3 * 12288];                           // 64 x 256 fp16

  int bh = blockIdx.x;
  int b = bh >> 3, h = bh & 7;
  int t = threadIdx.x;
  int lane = t & 63, wave = t >> 6;             // wave 0..7
  int ln15 = lane & 15, kh = lane >> 4;
  int rowq = (lane >> 4) * 4;

  const short* gM = (const short*)M16 + (size_t)bh * IDF * CDF;
  const short* gT = (const short*)cT16 + (size_t)b * LL * CDF;
  const short* gC = (const short*)ctx16 + (size_t)b * CDF * LL;

  int offA[4], offB[2], rowM[4], rmask[4];
#pragma unroll
  for (int r = 0; r < 4; ++r) {
    int row = r * 16 + ln15;
    offA[r] = row * 32 + ((kh ^ ((row >> 1) & 3)) * 8);
    rowM[r] = row * 256;
    rmask[r] = row & 7;
  }
#pragma unroll
  for (int c = 0; c < 2; ++c) {
    int row = wave * 32 + c * 16 + ln15;       // 0..255
    offB[c] = 2048 + row * 32 + ((kh ^ ((row >> 1) & 3)) * 8);
  }

  f32x4 acc[4][2] = {};

  // ===== Phase 2: logits = M x cT^T, K=256 =====
  st_p2(&S[0],         gM, gT, wave, lane, 0);
  st_p2(&S[12288],     gM, gT, wave, lane, 32);
  st_p2(&S[2 * 12288], gM, gT, wave, lane, 64);
  int cur = 0;
  {
    const int NSTEP = 8;
#pragma unroll 1
    for (int ks = 0; ks < NSTEP; ++ks) {
      short* Sc = &S[cur * 12288];
      WAIT_ENTER3(6, 3)
      half8v fa[4], fb[2];
#pragma unroll
      for (int r = 0; r < 4; ++r)
        fa[r] = *reinterpret_cast<const half8v*>(&Sc[offA[r]]);
#pragma unroll
      for (int c = 0; c < 2; ++c)
        fb[c] = *reinterpret_cast<const half8v*>(&Sc[offB[c]]);
      __builtin_amdgcn_s_setprio(1);
#pragma unroll
      for (int r = 0; r < 4; ++r)
#pragma unroll
        for (int c = 0; c < 2; ++c)
          acc[r][c] = __builtin_amdgcn_mfma_f32_16x16x32_f16(fa[r], fb[c], acc[r][c], 0, 0, 0);
      __builtin_amdgcn_s_setprio(0);
      BAR_EXIT()
      if (ks + 3 < NSTEP)
        st_p2(Sc, gM, gT, wave, lane, (ks + 3) * 32);
      cur = (cur == 2) ? 0 : cur + 1;
    }
  }

  // Prefetch phase-3 B (ctx16) BEFORE softmax; stays in flight (LDS_BAR only).
  st_pB(&S[0],         gC, LL, wave, lane, 0);
  st_pB(&S[12288],     gC, LL, wave, lane, 32);
  st_pB(&S[2 * 12288], gC, LL, wave, lane, 64);

  // ===== Softmax over l. pm in P_lds region. =====
  float* pm = reinterpret_cast<float*>(P_lds);   // 64*8 floats
  float gmax[4][4], ginv[4][4];
#pragma unroll
  for (int r = 0; r < 4; ++r)
#pragma unroll
    for (int reg = 0; reg < 4; ++reg) {
      float m = fmaxf(acc[r][0][reg], acc[r][1][reg]);
#pragma unroll
      for (int msk = 8; msk >= 1; msk >>= 1) m = fmaxf(m, __shfl_xor(m, msk, 64));
      if (ln15 == 0) pm[(r * 16 + rowq + reg) * 8 + wave] = m;
    }
  LDS_BAR()
#pragma unroll
  for (int r = 0; r < 4; ++r)
#pragma unroll
    for (int reg = 0; reg < 4; ++reg) {
      int row = r * 16 + rowq + reg;
      float4 p0 = *reinterpret_cast<const float4*>(&pm[row * 8]);
      float4 p1 = *reinterpret_cast<const float4*>(&pm[row * 8 + 4]);
      gmax[r][reg] = fmaxf(fmaxf(fmaxf(p0.x, p0.y), fmaxf(p0.z, p0.w)),
                           fmaxf(fmaxf(p1.x, p1.y), fmaxf(p1.z, p1.w)));
    }
  LDS_BAR()
#pragma unroll
  for (int r = 0; r < 4; ++r)
#pragma unroll
    for (int reg = 0; reg < 4; ++reg) {
      acc[r][0][reg] = __expf(acc[r][0][reg] - gmax[r][reg]);
      acc[r][1][reg] = __expf(acc[r][1][reg] - gmax[r][reg]);
      float s = acc[r][0][reg] + acc[r][1][reg];
#pragma unroll
      for (int msk = 8; msk >= 1; msk >>= 1) s += __shfl_xor(s, msk, 64);
      if (ln15 == 0) pm[(r * 16 + rowq + reg) * 8 + wave] = s;
    }
  LDS_BAR()
#pragma unroll
  for (int r = 0; r < 4; ++r)
#pragma unroll
    for (int reg = 0; reg < 4; ++reg) {
      int row = r * 16 + rowq + reg;
      float4 p0 = *reinterpret_cast<const float4*>(&pm[row * 8]);
      float4 p1 = *reinterpret_cast<const float4*>(&pm[row * 8 + 4]);
      ginv[r][reg] = 1.f / (p0.x + p0.y + p0.z + p0.w + p1.x + p1.y + p1.z + p1.w);
    }
  LDS_BAR()   // pm fully consumed before P overwrites the region

  // P -> global (for epilogue) and -> P_lds (phase-3 A operand)
  size_t pbase = (size_t)bh * IDF * LL;
#pragma unroll
  for (int r = 0; r < 4; ++r)
#pragma unroll
    for (int c = 0; c < 2; ++c)
#pragma unroll
      for (int reg = 0; reg < 4; ++reg) {
        float p = acc[r][c][reg] * ginv[r][reg];
        int row = r * 16 + rowq + reg;
        int col = wave * 32 + c * 16 + ln15;
        unsigned short ph = f2h(p);
        P16[pbase + (size_t)row * LL + col] = ph;
        P_lds[row * 256 + ((((col >> 3) ^ (row & 7)) << 3) + (col & 7))] = (short)ph;
      }
  LDS_BAR()

  // ===== Phase 3: N2 = P x ctx^T, K=256. A from P_lds. =====
#pragma unroll
  for (int r = 0; r < 4; ++r)
#pragma unroll
    for (int c = 0; c < 2; ++c) acc[r][c] = (f32x4){0.f, 0.f, 0.f, 0.f};
  cur = 0;
  {
    const int NSTEP = 8;
#pragma unroll 1
    for (int ks = 0; ks < NSTEP; ++ks) {
      short* Sc = &S[cur * 12288];
      WAIT_ENTER3(4, 2)
      half8v fa[4], fb[2];
#pragma unroll
      for (int r = 0; r < 4; ++r) {
        int ck = ((ks * 4 + kh) ^ rmask[r]) << 3;
        fa[r] = *reinterpret_cast<const half8v*>(&P_lds[rowM[r] + ck]);
      }
#pragma unroll
      for (int c = 0; c < 2; ++c)
        fb[c] = *reinterpret_cast<const half8v*>(&Sc[offB[c]]);
      __builtin_amdgcn_s_setprio(1);
#pragma unroll
      for (int r = 0; r < 4; ++r)
#pragma unroll
        for (int c = 0; c < 2; ++c)
          acc[r][c] = __builtin_amdgcn_mfma_f32_16x16x32_f16(fa[r], fb[c], acc[r][c], 0, 0, 0);
      __builtin_amdgcn_s_setprio(0);
      BAR_EXIT()
      if (ks + 3 < NSTEP)
        st_pB(Sc, gC, LL, wave, lane, (ks + 3) * 32);
      cur = (cur == 2) ? 0 : cur + 1;
    }
  }

  size_t nbase = (size_t)b * IDF * KHC + h * CDF;
#pragma unroll
  for (int r = 0; r < 4; ++r)
#pragma unroll
    for (int c = 0; c < 2; ++c)
#pragma unroll
      for (int reg = 0; reg < 4; ++reg) {
        size_t idx = nbase + (size_t)(r * 16 + rowq + reg) * KHC + wave * 32 + c * 16 + ln15;
        N216[idx] = f2h(acc[r][c][reg]);
      }
}

// ---------------------------------------------------------------------------
// K4 (MFMA fp16, 3-deep): ctx_out[b][i][o] = sum_{hc} N2*W. UNCHANGED.
// ---------------------------------------------------------------------------
__device__ __forceinline__ void k4_stage(short* dst,
                                         const short* gA, const short* gB,
                                         int wave, int lane, int kk0, int obase) {
  int h4 = kk0 >> 8, cb = kk0 & 255;
#pragma unroll
  for (int j = 0; j < 3; ++j) {
    int inst = wave * 3 + j;               // 0..11
    if (inst < 4) {
      int rb = inst * 16;
      int r  = rb + (lane >> 2);
      int gc = (lane & 3) ^ ((r >> 1) & 3);
      GLDS16(gA + (size_t)r * KHC + kk0 + gc * 8, dst + rb * 32);
    } else {
      int rb = (inst - 4) * 16;
      int r  = rb + (lane >> 2);
      int gc = (lane & 3) ^ ((r >> 1) & 3);
      GLDS16(gB + (size_t)(h4 * SSZ + obase + r) * CDF + cb + gc * 8,
             dst + 2048 + rb * 32);
    }
  }
}

__global__ __launch_bounds__(256) void k4_mfma(const unsigned short* __restrict__ N216,
                                               const unsigned short* __restrict__ W16,
                                               float* __restrict__ out0,
                                               float* __restrict__ out1) {
  __shared__ __align__(16) short S[3 * 6144];   // 36 KB

  int blk = blockIdx.x;
  int g = blk >> 8;
  int r8 = blk & 255;
  int b = r8 >> 3, ot = r8 & 7;
  int obase = ot * 128;
  int t = threadIdx.x;
  int lane = t & 63, wave = t >> 6;
  int ln15 = lane & 15, kh = lane >> 4;

  const short* gA = (const short*)N216 + (size_t)b * IDF * KHC;
  const short* gB = (const short*)W16;

  int offA[4], offB[2];
#pragma unroll
  for (int r = 0; r < 4; ++r) {
    int row = r * 16 + ln15;
    offA[r] = row * 32 + ((kh ^ ((row >> 1) & 3)) * 8);
  }
#pragma unroll
  for (int c = 0; c < 2; ++c) {
    int row = wave * 32 + c * 16 + ln15;
    offB[c] = 2048 + row * 32 + ((kh ^ ((row >> 1) & 3)) * 8);
  }

  int kbase = g * (KHC / 2);
  f32x4 acc[4][2] = {};

  k4_stage(&S[0],        gA, gB, wave, lane, kbase, obase);
  k4_stage(&S[6144],     gA, gB, wave, lane, kbase + 32, obase);
  k4_stage(&S[2 * 6144], gA, gB, wave, lane, kbase + 64, obase);
  int cur = 0;

  const int NSTEP = 32;
#pragma unroll 1
  for (int ks = 0; ks < NSTEP; ++ks) {
    short* Sc = &S[cur * 6144];
    WAIT_ENTER3(6, 3)
    half8v fa[4], fb[2];
#pragma unroll
    for (int r = 0; r < 4; ++r)
      fa[r] = *reinterpret_cast<const half8v*>(&Sc[offA[r]]);
#pragma unroll
    for (int c = 0; c < 2; ++c)
      fb[c] = *reinterpret_cast<const half8v*>(&Sc[offB[c]]);
    __builtin_amdgcn_s_setprio(1);
#pragma unroll
    for (int r = 0; r < 4; ++r)
#pragma unroll
      for (int c = 0; c < 2; ++c)
        acc[r][c] = __builtin_amdgcn_mfma_f32_16x16x32_f16(fa[r], fb[c], acc[r][c], 0, 0, 0);
    __builtin_amdgcn_s_setprio(0);
    BAR_EXIT()
    if (ks + 3 < NSTEP)
      k4_stage(Sc, gA, gB, wave, lane, kbase + (ks + 3) * 32, obase);
    cur = (cur == 2) ? 0 : cur + 1;
  }

  float* dst = (g == 0) ? out0 : out1;
  int rowq = (lane >> 4) * 4;
#pragma unroll
  for (int r = 0; r < 4; ++r)
#pragma unroll
    for (int c = 0; c < 2; ++c)
#pragma unroll
      for (int reg = 0; reg < 4; ++reg)
        dst[((size_t)b * IDF + r * 16 + rowq + reg) * SSZ +
            obase + wave * 32 + c * 16 + ln15] = acc[r][c][reg];
}

// ---------------------------------------------------------------------------
// Fused epilogue: blocks 0..127 -> attn_out[b][l][i] = sum_h P16[bh][i][l];
// blocks 128..2175 -> out[idx] += Pbuf[idx] (k4 g=1 partial).
// ---------------------------------------------------------------------------
__global__ __launch_bounds__(256) void k_epi(const unsigned short* __restrict__ P16,
                                             float* __restrict__ outa,
                                             float* __restrict__ out,
                                             const float* __restrict__ Pbuf) {
  int blk0 = blockIdx.x;
  int tid = threadIdx.x;
  if (blk0 >= 128) {                       // out += Pbuf
    int idx = (blk0 - 128) * 256 + tid;
    float4 a = reinterpret_cast<float4*>(out)[idx];
    float4 p = reinterpret_cast<const float4*>(Pbuf)[idx];
    a.x += p.x; a.y += p.y; a.z += p.z; a.w += p.w;
    reinterpret_cast<float4*>(out)[idx] = a;
    return;
  }
  __shared__ float T[64][65];
  int b = blk0 >> 2, lt = blk0 & 3;
  int l0 = lt * 64;
  float4 acc[4];
#pragma unroll
  for (int p = 0; p < 4; ++p) acc[p] = make_float4(0.f, 0.f, 0.f, 0.f);
  for (int h = 0; h < NH; ++h) {
    size_t src = (size_t)(b * NH + h) * IDF * LL;
#pragma unroll
    for (int p = 0; p < 4; ++p) {
      int f = tid + p * 256;
      int i = f >> 4, lc = (f & 15) * 4;
      ushort4 u = *reinterpret_cast<const ushort4*>(&P16[src + i * LL + l0 + lc]);
      acc[p].x += h2f(u.x); acc[p].y += h2f(u.y);
      acc[p].z += h2f(u.z); acc[p].w += h2f(u.w);
    }
  }
#pragma unroll
  for (int p = 0; p < 4; ++p) {
    int f = tid + p * 256;
    int i = f >> 4, lc = (f & 15) * 4;
    T[i][lc + 0] = acc[p].x; T[i][lc + 1] = acc[p].y;
    T[i][lc + 2] = acc[p].z; T[i][lc + 3] = acc[p].w;
  }
  __syncthreads();
#pragma unroll
  for (int p = 0; p < 4; ++p) {
    int f = tid + p * 256;
    int lr = f >> 4, ic = (f & 15) * 4;
    float4 v = {T[ic + 0][lr], T[ic + 1][lr], T[ic + 2][lr], T[ic + 3][lr]};
    *reinterpret_cast<float4*>(&outa[((size_t)b * LL + l0 + lr) * IDF + ic]) = v;
  }
}

// ---------------------------------------------------------------------------
extern "C" void kernel_launch(void* const* d_in, const int* in_sizes, int n_in,
                              void* d_out, int out_size, void* d_ws, size_t ws_size,
                              hipStream_t stream) {
  const float* wc  = (const float*)d_in[0];   // [32][64][1024]
  const float* ctx = (const float*)d_in[1];   // [32][256][256]
  const float* W   = (const float*)d_in[2];   // [8][1024][256]
  float* out = (float*)d_out;

  const size_t NE = 2097152;   // elems of wc == W == ctx
  const size_t NM = 4194304;   // elems of M == P == N2
  unsigned short* p = (unsigned short*)d_ws;
  unsigned short *wc16 = p;   p += NE;
  unsigned short *Wt16 = p;   p += NE;
  unsigned short *W16  = p;   p += NE;
  unsigned short *ctx16 = p;  p += NE;
  unsigned short *cT16 = p;   p += NE;
  unsigned short *M16  = p;   p += NM;
  unsigned short *P16  = p;   p += NM;
  unsigned short *N216 = p;   p += NM;
  float* Pbuf = (float*)p;    // 2.1M floats

  k_prep  <<<7168, 256, 0, stream>>>(wc, W, ctx, wc16, W16, ctx16, Wt16, cT16);
  k1_mfma <<<BB * NH * 2, 256, 0, stream>>>(wc16, Wt16, M16);
  k23     <<<BB * NH, 512, 0, stream>>>(M16, cT16, ctx16, P16, N216);
  k4_mfma <<<512, 256, 0, stream>>>(N216, W16, out, Pbuf);
  k_epi   <<<2176, 256, 0, stream>>>(P16, out + (size_t)BB * IDF * SSZ, out, Pbuf);
}

// Round 19
// 80.279 us; speedup vs baseline: 1.0245x; 1.0245x over previous
//
#include <hip/hip_runtime.h>
#include <hip/hip_bf16.h>

#define BB 32
#define IDF 64
#define CDF 256
#define SSZ 1024
#define NH 8
#define LL 256
#define KHC 2048   // NH*CDF

typedef __attribute__((ext_vector_type(8))) _Float16 half8v;   // 8 fp16
typedef __attribute__((ext_vector_type(4))) float f32x4;       // MFMA acc

// async global->LDS, 16B per lane, LDS dest = wave-uniform base + lane*16
#define GLDS16(g, l) __builtin_amdgcn_global_load_lds(                        \
    (const __attribute__((address_space(1))) void*)(g),                       \
    (__attribute__((address_space(3))) void*)(l), 16, 0, 0)

// 3-deep pipeline phase entry (T3+T4): wait only for the CURRENT buffer's
// DMA, leaving the next TWO stages in flight. Never vmcnt(0) mid-loop.
#define WAIT_ENTER3(NFULL, NHALF)                                             \
  { if (ks < NSTEP - 2)                                                       \
      asm volatile("s_waitcnt vmcnt(" #NFULL ")" ::: "memory");               \
    else if (ks == NSTEP - 2)                                                 \
      asm volatile("s_waitcnt vmcnt(" #NHALF ")" ::: "memory");               \
    else                                                                      \
      asm volatile("s_waitcnt vmcnt(0)" ::: "memory");                        \
    __builtin_amdgcn_s_barrier();                                             \
    __builtin_amdgcn_sched_barrier(0); }
#define BAR_EXIT()                                                            \
  { __builtin_amdgcn_sched_barrier(0);                                        \
    __builtin_amdgcn_s_barrier();                                             \
    __builtin_amdgcn_sched_barrier(0); }
// LDS-only barrier: drains ds ops but leaves global_load_lds (vmcnt) in
// flight — lets phase-3 prefetch ride through the softmax.
#define LDS_BAR()                                                             \
  { asm volatile("s_waitcnt lgkmcnt(0)" ::: "memory");                        \
    __builtin_amdgcn_s_barrier();                                             \
    __builtin_amdgcn_sched_barrier(0); }

__device__ inline unsigned short f2h(float x) {
  _Float16 h = (_Float16)x;
  return *reinterpret_cast<unsigned short*>(&h);
}
__device__ inline float h2f(unsigned short u) {
  _Float16 h = *reinterpret_cast<_Float16*>(&u);
  return (float)h;
}

// ---------------------------------------------------------------------------
// Fused prep: blocks 0..6143 elementwise casts (wc,W,ctx -> fp16);
// blocks 6144..6655 -> Wt16 [h][c][o]; 6656..7167 -> cT16 [b][l][c].
// ---------------------------------------------------------------------------
__global__ __launch_bounds__(256) void k_prep(const float* __restrict__ wc,
                                              const float* __restrict__ W,
                                              const float* __restrict__ ctx,
                                              unsigned short* __restrict__ wc16,
                                              unsigned short* __restrict__ W16,
                                              unsigned short* __restrict__ ctx16,
                                              unsigned short* __restrict__ Wt16,
                                              unsigned short* __restrict__ cT16) {
  __shared__ float Tt[64][65];
  int blk0 = blockIdx.x;
  int t = threadIdx.x;
  if (blk0 < 6144) {                       // elementwise casts
    int sel = blk0 >> 11;
    int idx = ((blk0 & 2047) * 256 + t) * 4;
    const float* src = (sel == 0) ? wc : (sel == 1) ? W : ctx;
    unsigned short* d = (sel == 0) ? wc16 : (sel == 1) ? W16 : ctx16;
    float4 v = *reinterpret_cast<const float4*>(&src[idx]);
    __align__(8) unsigned short h[4] = {f2h(v.x), f2h(v.y), f2h(v.z), f2h(v.w)};
    *reinterpret_cast<int2*>(&d[idx]) = *reinterpret_cast<int2*>(h);
  } else if (blk0 < 6656) {                // W -> Wt16 [h][c][o]
    int blk = blk0 - 6144;
    int h = blk >> 6, ot = (blk >> 2) & 15, cq = blk & 3;
    int og = ot * 64, cg = cq * 64;
    int o_l = t >> 4, c4 = (t & 15) * 4;
#pragma unroll
    for (int p = 0; p < 4; ++p) {
      int o = o_l + 16 * p;
      float4 v = *reinterpret_cast<const float4*>(
          &W[((size_t)h * SSZ + og + o) * CDF + cg + c4]);
      Tt[c4 + 0][o] = v.x; Tt[c4 + 1][o] = v.y;
      Tt[c4 + 2][o] = v.z; Tt[c4 + 3][o] = v.w;
    }
    __syncthreads();
    int c_l = t >> 2;
#pragma unroll
    for (int p = 0; p < 4; ++p) {
      int o0 = ((t & 3) + 4 * p) * 4;
      __align__(8) unsigned short hv[4];
#pragma unroll
      for (int j = 0; j < 4; ++j) hv[j] = f2h(Tt[c_l][o0 + j]);
      size_t base = ((size_t)h * CDF + cg + c_l) * SSZ + og + o0;
      *reinterpret_cast<int2*>(&Wt16[base]) = *reinterpret_cast<int2*>(hv);
    }
  } else {                                 // ctx -> cT16 [b][l][c]
    int blk = blk0 - 6656;
    int b = blk >> 4, cq = (blk >> 2) & 3, lt = blk & 3;
    int cg = cq * 64, lg = lt * 64;
    int c_l = t >> 4, l4 = (t & 15) * 4;
#pragma unroll
    for (int p = 0; p < 4; ++p) {
      int c = c_l + 16 * p;
      float4 v = *reinterpret_cast<const float4*>(
          &ctx[((size_t)b * CDF + cg + c) * LL + lg + l4]);
      Tt[l4 + 0][c] = v.x; Tt[l4 + 1][c] = v.y;
      Tt[l4 + 2][c] = v.z; Tt[l4 + 3][c] = v.w;
    }
    __syncthreads();
    int l_l = t >> 2;
#pragma unroll
    for (int p = 0; p < 4; ++p) {
      int c0 = ((t & 3) + 4 * p) * 4;
      __align__(8) unsigned short hv[4];
#pragma unroll
      for (int j = 0; j < 4; ++j) hv[j] = f2h(Tt[l_l][c0 + j]);
      size_t base = ((size_t)b * LL + lg + l_l) * CDF + cg + c0;
      *reinterpret_cast<int2*>(&cT16[base]) = *reinterpret_cast<int2*>(hv);
    }
  }
}

// ---------------------------------------------------------------------------
// k123: fused K1+K2+K3. grid 512 = (bh, i-half): each 256-thr block (4 waves)
// owns 32 i-rows x 256 cols -> 2 blocks/CU, independent barrier domains
// (restores the m114 cross-block overlap the 8-wave fused version lost,
// while keeping the M/P LDS-residency wins). Wave tile: 32i x 64col,
// acc[2][4]. Softmax is over cols, which stay intact per block.
// LDS: 3 x 20KB staging (A 2KB + B 16KB + dup 2KB) + 16KB M/P_lds = 76 KB.
// Phase 1: M = wc x Wt^T (K=1024, 32 steps, 5 GLDS/wave) -> M_lds
// Phase 2: logits = M_lds x cT^T (K=256, 8 steps, 4 GLDS/wave) -> softmax
//          -> P (global + M_lds)
// Phase 3: N2 = P_lds x ctx^T (K=256, 8 steps) -> N216
// ---------------------------------------------------------------------------
#define BUF_SH 10240   // shorts per staging buffer (A 1024 + B 8192 + dup 1024)

__device__ __forceinline__ void st_p1(short* dst, const short* gA, const short* gB,
                                      int wave, int lane, int k0) {
#pragma unroll
  for (int j = 0; j < 5; ++j) {
    int inst = wave * 5 + j;               // 0..19
    const short* src; int toff, rb;
    if (inst < 2)       { src = gA; toff = 0;    rb = inst * 16; }
    else if (inst < 18) { src = gB; toff = 1024; rb = (inst - 2) * 16; }
    else                { src = gA; toff = 9216; rb = (inst - 18) * 16; } // dup
    int r  = rb + (lane >> 2);
    int gc = (lane & 3) ^ ((r >> 1) & 3);
    GLDS16(src + (size_t)r * SSZ + k0 + gc * 8, dst + toff + rb * 32);
  }
}
__device__ __forceinline__ void st_pB(short* dst, const short* gB, int ld,
                                      int wave, int lane, int k0) {
#pragma unroll
  for (int j = 0; j < 4; ++j) {
    int rb = (wave * 4 + j) * 16;          // 0..255 rows
    int r  = rb + (lane >> 2);
    int gc = (lane & 3) ^ ((r >> 1) & 3);
    GLDS16(gB + (size_t)r * ld + k0 + gc * 8, dst + 1024 + rb * 32);
  }
}

__global__ __launch_bounds__(256) void k123(const unsigned short* __restrict__ wc16,
                                            const unsigned short* __restrict__ Wt16,
                                            const unsigned short* __restrict__ cT16,
                                            const unsigned short* __restrict__ ctx16,
                                            unsigned short* __restrict__ P16,
                                            unsigned short* __restrict__ N216) {
  __shared__ __align__(16) short S[3 * BUF_SH + 8192];   // 76 KB
  short* P_lds = &S[3 * BUF_SH];                          // 32 x 256 fp16

  int blk = blockIdx.x;
  int bh = blk >> 1, ih = blk & 1;
  int b = bh >> 3, h = bh & 7;
  int ibase = ih * 32;
  int t = threadIdx.x;
  int lane = t & 63, wave = t >> 6;             // wave 0..3
  int ln15 = lane & 15, kh = lane >> 4;
  int rowq = (lane >> 4) * 4;

  const short* gA = (const short*)wc16 + (size_t)(b * IDF + ibase) * SSZ;
  const short* gB = (const short*)Wt16 + (size_t)h * CDF * SSZ;
  const short* gT = (const short*)cT16 + (size_t)b * LL * CDF;
  const short* gC = (const short*)ctx16 + (size_t)b * CDF * LL;

  int offA[2], offB[4], rowM[2], rmask[2];
#pragma unroll
  for (int r = 0; r < 2; ++r) {
    int row = r * 16 + ln15;                   // 0..31 local
    offA[r] = row * 32 + ((kh ^ ((row >> 1) & 3)) * 8);
    rowM[r] = row * 256;
    rmask[r] = row & 7;
  }
#pragma unroll
  for (int c = 0; c < 4; ++c) {
    int row = wave * 64 + c * 16 + ln15;       // 0..255
    offB[c] = 1024 + row * 32 + ((kh ^ ((row >> 1) & 3)) * 8);
  }

  f32x4 acc[2][4] = {};

  // ===== Phase 1: M = wc x Wt^T, K=1024 =====
  st_p1(&S[0],           gA, gB, wave, lane, 0);
  st_p1(&S[BUF_SH],      gA, gB, wave, lane, 32);
  st_p1(&S[2 * BUF_SH],  gA, gB, wave, lane, 64);
  int cur = 0;
  {
    const int NSTEP = 32;
#pragma unroll 1
    for (int ks = 0; ks < NSTEP; ++ks) {
      short* Sc = &S[cur * BUF_SH];
      WAIT_ENTER3(10, 5)
      half8v fa[2], fb[4];
#pragma unroll
      for (int r = 0; r < 2; ++r)
        fa[r] = *reinterpret_cast<const half8v*>(&Sc[offA[r]]);
#pragma unroll
      for (int c = 0; c < 4; ++c)
        fb[c] = *reinterpret_cast<const half8v*>(&Sc[offB[c]]);
      __builtin_amdgcn_s_setprio(1);
#pragma unroll
      for (int r = 0; r < 2; ++r)
#pragma unroll
        for (int c = 0; c < 4; ++c)
          acc[r][c] = __builtin_amdgcn_mfma_f32_16x16x32_f16(fa[r], fb[c], acc[r][c], 0, 0, 0);
      __builtin_amdgcn_s_setprio(0);
      BAR_EXIT()
      if (ks + 3 < NSTEP)
        st_p1(Sc, gA, gB, wave, lane, (ks + 3) * 32);
      cur = (cur == 2) ? 0 : cur + 1;
    }
  }
  // M -> M_lds (fp16, chunk-XOR(row&7))
#pragma unroll
  for (int r = 0; r < 2; ++r)
#pragma unroll
    for (int c = 0; c < 4; ++c)
#pragma unroll
      for (int reg = 0; reg < 4; ++reg) {
        int row = r * 16 + rowq + reg;         // 0..31 local
        int col = wave * 64 + c * 16 + ln15;   // 0..255
        P_lds[row * 256 + ((((col >> 3) ^ (row & 7)) << 3) + (col & 7))] =
            (short)f2h(acc[r][c][reg]);
      }
  LDS_BAR()

  // ===== Phase 2: logits = M_lds x cT^T, K=256 =====
#pragma unroll
  for (int r = 0; r < 2; ++r)
#pragma unroll
    for (int c = 0; c < 4; ++c) acc[r][c] = (f32x4){0.f, 0.f, 0.f, 0.f};
  st_pB(&S[0],          gT, CDF, wave, lane, 0);
  st_pB(&S[BUF_SH],     gT, CDF, wave, lane, 32);
  st_pB(&S[2 * BUF_SH], gT, CDF, wave, lane, 64);
  cur = 0;
  {
    const int NSTEP = 8;
#pragma unroll 1
    for (int ks = 0; ks < NSTEP; ++ks) {
      short* Sc = &S[cur * BUF_SH];
      WAIT_ENTER3(8, 4)
      half8v fa[2], fb[4];
#pragma unroll
      for (int r = 0; r < 2; ++r) {
        int ck = ((ks * 4 + kh) ^ rmask[r]) << 3;
        fa[r] = *reinterpret_cast<const half8v*>(&P_lds[rowM[r] + ck]);
      }
#pragma unroll
      for (int c = 0; c < 4; ++c)
        fb[c] = *reinterpret_cast<const half8v*>(&Sc[offB[c]]);
      __builtin_amdgcn_s_setprio(1);
#pragma unroll
      for (int r = 0; r < 2; ++r)
#pragma unroll
        for (int c = 0; c < 4; ++c)
          acc[r][c] = __builtin_amdgcn_mfma_f32_16x16x32_f16(fa[r], fb[c], acc[r][c], 0, 0, 0);
      __builtin_amdgcn_s_setprio(0);
      BAR_EXIT()
      if (ks + 3 < NSTEP)
        st_pB(Sc, gT, CDF, wave, lane, (ks + 3) * 32);
      cur = (cur == 2) ? 0 : cur + 1;
    }
  }

  // Prefetch phase-3 B (ctx16) BEFORE softmax; stays in flight (LDS_BAR only).
  st_pB(&S[0],          gC, LL, wave, lane, 0);
  st_pB(&S[BUF_SH],     gC, LL, wave, lane, 32);
  st_pB(&S[2 * BUF_SH], gC, LL, wave, lane, 64);

  // ===== Softmax over l (cols). pm in P_lds region (M dead). =====
  float* pm = reinterpret_cast<float*>(P_lds);   // 32 rows x 4 waves floats
  float gmax[2][4], ginv[2][4];
#pragma unroll
  for (int r = 0; r < 2; ++r)
#pragma unroll
    for (int reg = 0; reg < 4; ++reg) {
      float m = fmaxf(fmaxf(acc[r][0][reg], acc[r][1][reg]),
                      fmaxf(acc[r][2][reg], acc[r][3][reg]));
#pragma unroll
      for (int msk = 8; msk >= 1; msk >>= 1) m = fmaxf(m, __shfl_xor(m, msk, 64));
      if (ln15 == 0) pm[(r * 16 + rowq + reg) * 4 + wave] = m;
    }
  LDS_BAR()
#pragma unroll
  for (int r = 0; r < 2; ++r)
#pragma unroll
    for (int reg = 0; reg < 4; ++reg) {
      int row = r * 16 + rowq + reg;
      float4 p0 = *reinterpret_cast<const float4*>(&pm[row * 4]);
      gmax[r][reg] = fmaxf(fmaxf(p0.x, p0.y), fmaxf(p0.z, p0.w));
    }
  LDS_BAR()
#pragma unroll
  for (int r = 0; r < 2; ++r)
#pragma unroll
    for (int reg = 0; reg < 4; ++reg) {
      float s = 0.f;
#pragma unroll
      for (int c = 0; c < 4; ++c) {
        acc[r][c][reg] = __expf(acc[r][c][reg] - gmax[r][reg]);
        s += acc[r][c][reg];
      }
#pragma unroll
      for (int msk = 8; msk >= 1; msk >>= 1) s += __shfl_xor(s, msk, 64);
      if (ln15 == 0) pm[(r * 16 + rowq + reg) * 4 + wave] = s;
    }
  LDS_BAR()
#pragma unroll
  for (int r = 0; r < 2; ++r)
#pragma unroll
    for (int reg = 0; reg < 4; ++reg) {
      int row = r * 16 + rowq + reg;
      float4 p0 = *reinterpret_cast<const float4*>(&pm[row * 4]);
      ginv[r][reg] = 1.f / (p0.x + p0.y + p0.z + p0.w);
    }
  LDS_BAR()   // pm fully consumed before P overwrites the region

  // P -> global (for epilogue) and -> P_lds (phase-3 A operand)
  size_t pbase = (size_t)bh * IDF * LL + (size_t)ibase * LL;
#pragma unroll
  for (int r = 0; r < 2; ++r)
#pragma unroll
    for (int c = 0; c < 4; ++c)
#pragma unroll
      for (int reg = 0; reg < 4; ++reg) {
        float p = acc[r][c][reg] * ginv[r][reg];
        int row = r * 16 + rowq + reg;
        int col = wave * 64 + c * 16 + ln15;
        unsigned short ph = f2h(p);
        P16[pbase + (size_t)row * LL + col] = ph;
        P_lds[row * 256 + ((((col >> 3) ^ (row & 7)) << 3) + (col & 7))] = (short)ph;
      }
  LDS_BAR()

  // ===== Phase 3: N2 = P_lds x ctx^T, K=256 =====
#pragma unroll
  for (int r = 0; r < 2; ++r)
#pragma unroll
    for (int c = 0; c < 4; ++c) acc[r][c] = (f32x4){0.f, 0.f, 0.f, 0.f};
  cur = 0;
  {
    const int NSTEP = 8;
#pragma unroll 1
    for (int ks = 0; ks < NSTEP; ++ks) {
      short* Sc = &S[cur * BUF_SH];
      WAIT_ENTER3(8, 4)
      half8v fa[2], fb[4];
#pragma unroll
      for (int r = 0; r < 2; ++r) {
        int ck = ((ks * 4 + kh) ^ rmask[r]) << 3;
        fa[r] = *reinterpret_cast<const half8v*>(&P_lds[rowM[r] + ck]);
      }
#pragma unroll
      for (int c = 0; c < 4; ++c)
        fb[c] = *reinterpret_cast<const half8v*>(&Sc[offB[c]]);
      __builtin_amdgcn_s_setprio(1);
#pragma unroll
      for (int r = 0; r < 2; ++r)
#pragma unroll
        for (int c = 0; c < 4; ++c)
          acc[r][c] = __builtin_amdgcn_mfma_f32_16x16x32_f16(fa[r], fb[c], acc[r][c], 0, 0, 0);
      __builtin_amdgcn_s_setprio(0);
      BAR_EXIT()
      if (ks + 3 < NSTEP)
        st_pB(Sc, gC, LL, wave, lane, (ks + 3) * 32);
      cur = (cur == 2) ? 0 : cur + 1;
    }
  }

  size_t nbase = (size_t)b * IDF * KHC + (size_t)ibase * KHC + h * CDF;
#pragma unroll
  for (int r = 0; r < 2; ++r)
#pragma unroll
    for (int c = 0; c < 4; ++c)
#pragma unroll
      for (int reg = 0; reg < 4; ++reg) {
        int row = r * 16 + rowq + reg;
        int col = wave * 64 + c * 16 + ln15;
        N216[nbase + (size_t)row * KHC + col] = f2h(acc[r][c][reg]);
      }
}

// ---------------------------------------------------------------------------
// K4 (MFMA fp16, 3-deep): ctx_out[b][i][o] = sum_{hc} N2*W. UNCHANGED.
// ---------------------------------------------------------------------------
__device__ __forceinline__ void k4_stage(short* dst,
                                         const short* gA, const short* gB,
                                         int wave, int lane, int kk0, int obase) {
  int h4 = kk0 >> 8, cb = kk0 & 255;
#pragma unroll
  for (int j = 0; j < 3; ++j) {
    int inst = wave * 3 + j;               // 0..11
    if (inst < 4) {
      int rb = inst * 16;
      int r  = rb + (lane >> 2);
      int gc = (lane & 3) ^ ((r >> 1) & 3);
      GLDS16(gA + (size_t)r * KHC + kk0 + gc * 8, dst + rb * 32);
    } else {
      int rb = (inst - 4) * 16;
      int r  = rb + (lane >> 2);
      int gc = (lane & 3) ^ ((r >> 1) & 3);
      GLDS16(gB + (size_t)(h4 * SSZ + obase + r) * CDF + cb + gc * 8,
             dst + 2048 + rb * 32);
    }
  }
}

__global__ __launch_bounds__(256) void k4_mfma(const unsigned short* __restrict__ N216,
                                               const unsigned short* __restrict__ W16,
                                               float* __restrict__ out0,
                                               float* __restrict__ out1) {
  __shared__ __align__(16) short S[3 * 6144];   // 36 KB

  int blk = blockIdx.x;
  int g = blk >> 8;
  int r8 = blk & 255;
  int b = r8 >> 3, ot = r8 & 7;
  int obase = ot * 128;
  int t = threadIdx.x;
  int lane = t & 63, wave = t >> 6;
  int ln15 = lane & 15, kh = lane >> 4;

  const short* gA = (const short*)N216 + (size_t)b * IDF * KHC;
  const short* gB = (const short*)W16;

  int offA[4], offB[2];
#pragma unroll
  for (int r = 0; r < 4; ++r) {
    int row = r * 16 + ln15;
    offA[r] = row * 32 + ((kh ^ ((row >> 1) & 3)) * 8);
  }
#pragma unroll
  for (int c = 0; c < 2; ++c) {
    int row = wave * 32 + c * 16 + ln15;
    offB[c] = 2048 + row * 32 + ((kh ^ ((row >> 1) & 3)) * 8);
  }

  int kbase = g * (KHC / 2);
  f32x4 acc[4][2] = {};

  k4_stage(&S[0],        gA, gB, wave, lane, kbase, obase);
  k4_stage(&S[6144],     gA, gB, wave, lane, kbase + 32, obase);
  k4_stage(&S[2 * 6144], gA, gB, wave, lane, kbase + 64, obase);
  int cur = 0;

  const int NSTEP = 32;
#pragma unroll 1
  for (int ks = 0; ks < NSTEP; ++ks) {
    short* Sc = &S[cur * 6144];
    WAIT_ENTER3(6, 3)
    half8v fa[4], fb[2];
#pragma unroll
    for (int r = 0; r < 4; ++r)
      fa[r] = *reinterpret_cast<const half8v*>(&Sc[offA[r]]);
#pragma unroll
    for (int c = 0; c < 2; ++c)
      fb[c] = *reinterpret_cast<const half8v*>(&Sc[offB[c]]);
    __builtin_amdgcn_s_setprio(1);
#pragma unroll
    for (int r = 0; r < 4; ++r)
#pragma unroll
      for (int c = 0; c < 2; ++c)
        acc[r][c] = __builtin_amdgcn_mfma_f32_16x16x32_f16(fa[r], fb[c], acc[r][c], 0, 0, 0);
    __builtin_amdgcn_s_setprio(0);
    BAR_EXIT()
    if (ks + 3 < NSTEP)
      k4_stage(Sc, gA, gB, wave, lane, kbase + (ks + 3) * 32, obase);
    cur = (cur == 2) ? 0 : cur + 1;
  }

  float* dst = (g == 0) ? out0 : out1;
  int rowq = (lane >> 4) * 4;
#pragma unroll
  for (int r = 0; r < 4; ++r)
#pragma unroll
    for (int c = 0; c < 2; ++c)
#pragma unroll
      for (int reg = 0; reg < 4; ++reg)
        dst[((size_t)b * IDF + r * 16 + rowq + reg) * SSZ +
            obase + wave * 32 + c * 16 + ln15] = acc[r][c][reg];
}

// ---------------------------------------------------------------------------
// Fused epilogue: blocks 0..127 -> attn_out[b][l][i] = sum_h P16[bh][i][l];
// blocks 128..2175 -> out[idx] += Pbuf[idx] (k4 g=1 partial).
// ---------------------------------------------------------------------------
__global__ __launch_bounds__(256) void k_epi(const unsigned short* __restrict__ P16,
                                             float* __restrict__ outa,
                                             float* __restrict__ out,
                                             const float* __restrict__ Pbuf) {
  int blk0 = blockIdx.x;
  int tid = threadIdx.x;
  if (blk0 >= 128) {                       // out += Pbuf
    int idx = (blk0 - 128) * 256 + tid;
    float4 a = reinterpret_cast<float4*>(out)[idx];
    float4 p = reinterpret_cast<const float4*>(Pbuf)[idx];
    a.x += p.x; a.y += p.y; a.z += p.z; a.w += p.w;
    reinterpret_cast<float4*>(out)[idx] = a;
    return;
  }
  __shared__ float T[64][65];
  int b = blk0 >> 2, lt = blk0 & 3;
  int l0 = lt * 64;
  float4 acc[4];
#pragma unroll
  for (int p = 0; p < 4; ++p) acc[p] = make_float4(0.f, 0.f, 0.f, 0.f);
  for (int h = 0; h < NH; ++h) {
    size_t src = (size_t)(b * NH + h) * IDF * LL;
#pragma unroll
    for (int p = 0; p < 4; ++p) {
      int f = tid + p * 256;
      int i = f >> 4, lc = (f & 15) * 4;
      ushort4 u = *reinterpret_cast<const ushort4*>(&P16[src + i * LL + l0 + lc]);
      acc[p].x += h2f(u.x); acc[p].y += h2f(u.y);
      acc[p].z += h2f(u.z); acc[p].w += h2f(u.w);
    }
  }
#pragma unroll
  for (int p = 0; p < 4; ++p) {
    int f = tid + p * 256;
    int i = f >> 4, lc = (f & 15) * 4;
    T[i][lc + 0] = acc[p].x; T[i][lc + 1] = acc[p].y;
    T[i][lc + 2] = acc[p].z; T[i][lc + 3] = acc[p].w;
  }
  __syncthreads();
#pragma unroll
  for (int p = 0; p < 4; ++p) {
    int f = tid + p * 256;
    int lr = f >> 4, ic = (f & 15) * 4;
    float4 v = {T[ic + 0][lr], T[ic + 1][lr], T[ic + 2][lr], T[ic + 3][lr]};
    *reinterpret_cast<float4*>(&outa[((size_t)b * LL + l0 + lr) * IDF + ic]) = v;
  }
}

// ---------------------------------------------------------------------------
extern "C" void kernel_launch(void* const* d_in, const int* in_sizes, int n_in,
                              void* d_out, int out_size, void* d_ws, size_t ws_size,
                              hipStream_t stream) {
  const float* wc  = (const float*)d_in[0];   // [32][64][1024]
  const float* ctx = (const float*)d_in[1];   // [32][256][256]
  const float* W   = (const float*)d_in[2];   // [8][1024][256]
  float* out = (float*)d_out;

  const size_t NE = 2097152;   // elems of wc == W == ctx
  const size_t NM = 4194304;   // elems of P == N2
  unsigned short* p = (unsigned short*)d_ws;
  unsigned short *wc16 = p;   p += NE;
  unsigned short *Wt16 = p;   p += NE;
  unsigned short *W16  = p;   p += NE;
  unsigned short *ctx16 = p;  p += NE;
  unsigned short *cT16 = p;   p += NE;
  unsigned short *P16  = p;   p += NM;
  unsigned short *N216 = p;   p += NM;
  float* Pbuf = (float*)p;    // 2.1M floats

  k_prep  <<<7168, 256, 0, stream>>>(wc, W, ctx, wc16, W16, ctx16, Wt16, cT16);
  k123    <<<BB * NH * 2, 256, 0, stream>>>(wc16, Wt16, cT16, ctx16, P16, N216);
  k4_mfma <<<512, 256, 0, stream>>>(N216, W16, out, Pbuf);
  k_epi   <<<2176, 256, 0, stream>>>(P16, out + (size_t)BB * IDF * SSZ, out, Pbuf);
}

// Round 20
// 78.210 us; speedup vs baseline: 1.0516x; 1.0265x over previous
//
#include <hip/hip_runtime.h>
#include <hip/hip_bf16.h>

#define BB 32
#define IDF 64
#define CDF 256
#define SSZ 1024
#define NH 8
#define LL 256
#define KHC 2048   // NH*CDF

typedef __attribute__((ext_vector_type(8))) _Float16 half8v;   // 8 fp16
typedef __attribute__((ext_vector_type(4))) float f32x4;       // MFMA acc

// async global->LDS, 16B per lane, LDS dest = wave-uniform base + lane*16
#define GLDS16(g, l) __builtin_amdgcn_global_load_lds(                        \
    (const __attribute__((address_space(1))) void*)(g),                       \
    (__attribute__((address_space(3))) void*)(l), 16, 0, 0)

// 3-deep pipeline phase entry (T3+T4): wait only for the CURRENT buffer's
// DMA, leaving the next TWO stages in flight. Never vmcnt(0) mid-loop.
#define WAIT_ENTER3(NFULL, NHALF)                                             \
  { if (ks < NSTEP - 2)                                                       \
      asm volatile("s_waitcnt vmcnt(" #NFULL ")" ::: "memory");               \
    else if (ks == NSTEP - 2)                                                 \
      asm volatile("s_waitcnt vmcnt(" #NHALF ")" ::: "memory");               \
    else                                                                      \
      asm volatile("s_waitcnt vmcnt(0)" ::: "memory");                        \
    __builtin_amdgcn_s_barrier();                                             \
    __builtin_amdgcn_sched_barrier(0); }
#define BAR_EXIT()                                                            \
  { __builtin_amdgcn_sched_barrier(0);                                        \
    __builtin_amdgcn_s_barrier();                                             \
    __builtin_amdgcn_sched_barrier(0); }
// LDS-only barrier: drains ds ops but leaves global_load_lds (vmcnt) in
// flight — lets phase-3 prefetch ride through the softmax.
#define LDS_BAR()                                                             \
  { asm volatile("s_waitcnt lgkmcnt(0)" ::: "memory");                        \
    __builtin_amdgcn_s_barrier();                                             \
    __builtin_amdgcn_sched_barrier(0); }

__device__ inline unsigned short f2h(float x) {
  _Float16 h = (_Float16)x;
  return *reinterpret_cast<unsigned short*>(&h);
}
__device__ inline float h2f(unsigned short u) {
  _Float16 h = *reinterpret_cast<_Float16*>(&u);
  return (float)h;
}

// ---------------------------------------------------------------------------
// Fused prep: blocks 0..6143 elementwise casts (wc,W,ctx -> fp16);
// blocks 6144..6655 -> Wt16 [h][c][o]; 6656..7167 -> cT16 [b][l][c].
// ---------------------------------------------------------------------------
__global__ __launch_bounds__(256) void k_prep(const float* __restrict__ wc,
                                              const float* __restrict__ W,
                                              const float* __restrict__ ctx,
                                              unsigned short* __restrict__ wc16,
                                              unsigned short* __restrict__ W16,
                                              unsigned short* __restrict__ ctx16,
                                              unsigned short* __restrict__ Wt16,
                                              unsigned short* __restrict__ cT16) {
  __shared__ float Tt[64][65];
  int blk0 = blockIdx.x;
  int t = threadIdx.x;
  if (blk0 < 6144) {                       // elementwise casts
    int sel = blk0 >> 11;
    int idx = ((blk0 & 2047) * 256 + t) * 4;
    const float* src = (sel == 0) ? wc : (sel == 1) ? W : ctx;
    unsigned short* d = (sel == 0) ? wc16 : (sel == 1) ? W16 : ctx16;
    float4 v = *reinterpret_cast<const float4*>(&src[idx]);
    __align__(8) unsigned short h[4] = {f2h(v.x), f2h(v.y), f2h(v.z), f2h(v.w)};
    *reinterpret_cast<int2*>(&d[idx]) = *reinterpret_cast<int2*>(h);
  } else if (blk0 < 6656) {                // W -> Wt16 [h][c][o]
    int blk = blk0 - 6144;
    int h = blk >> 6, ot = (blk >> 2) & 15, cq = blk & 3;
    int og = ot * 64, cg = cq * 64;
    int o_l = t >> 4, c4 = (t & 15) * 4;
#pragma unroll
    for (int p = 0; p < 4; ++p) {
      int o = o_l + 16 * p;
      float4 v = *reinterpret_cast<const float4*>(
          &W[((size_t)h * SSZ + og + o) * CDF + cg + c4]);
      Tt[c4 + 0][o] = v.x; Tt[c4 + 1][o] = v.y;
      Tt[c4 + 2][o] = v.z; Tt[c4 + 3][o] = v.w;
    }
    __syncthreads();
    int c_l = t >> 2;
#pragma unroll
    for (int p = 0; p < 4; ++p) {
      int o0 = ((t & 3) + 4 * p) * 4;
      __align__(8) unsigned short hv[4];
#pragma unroll
      for (int j = 0; j < 4; ++j) hv[j] = f2h(Tt[c_l][o0 + j]);
      size_t base = ((size_t)h * CDF + cg + c_l) * SSZ + og + o0;
      *reinterpret_cast<int2*>(&Wt16[base]) = *reinterpret_cast<int2*>(hv);
    }
  } else {                                 // ctx -> cT16 [b][l][c]
    int blk = blk0 - 6656;
    int b = blk >> 4, cq = (blk >> 2) & 3, lt = blk & 3;
    int cg = cq * 64, lg = lt * 64;
    int c_l = t >> 4, l4 = (t & 15) * 4;
#pragma unroll
    for (int p = 0; p < 4; ++p) {
      int c = c_l + 16 * p;
      float4 v = *reinterpret_cast<const float4*>(
          &ctx[((size_t)b * CDF + cg + c) * LL + lg + l4]);
      Tt[l4 + 0][c] = v.x; Tt[l4 + 1][c] = v.y;
      Tt[l4 + 2][c] = v.z; Tt[l4 + 3][c] = v.w;
    }
    __syncthreads();
    int l_l = t >> 2;
#pragma unroll
    for (int p = 0; p < 4; ++p) {
      int c0 = ((t & 3) + 4 * p) * 4;
      __align__(8) unsigned short hv[4];
#pragma unroll
      for (int j = 0; j < 4; ++j) hv[j] = f2h(Tt[l_l][c0 + j]);
      size_t base = ((size_t)b * LL + lg + l_l) * CDF + cg + c0;
      *reinterpret_cast<int2*>(&cT16[base]) = *reinterpret_cast<int2*>(hv);
    }
  }
}

// ---------------------------------------------------------------------------
// k123: fused K1+K2+K3 with B-PANEL SHARING across 2 batches.
// grid 256 = (bp x ih x h): 512 thr = 8 waves = 2 groups of 4.
// Group g handles bh_g = ((bp*2+g), h), rows [ih*32, ih*32+32).
// Phase 1: M = wc x Wt^T (K=1024, 32 steps). Wt[h] staged ONCE for both
//   groups (the round-19 TA-DMA wall was 2x redundant B staging):
//   24 GLDS/step/CU vs 40 before. A: 2 groups x 32 rows.
// Phase 2: logits = M_lds x cT[b_g]^T (K=256, 8 steps, per-group B) ->
//   softmax (per group, cols intact) -> P (global + P_lds)
// Phase 3: N2 = P_lds x ctx[b_g]^T (K=256, 8 steps, per-group B)
// LDS: 3 x 32KB staging + 2 x 16KB P_lds = 128 KB. Wave tile 32i x 64c,
// acc[2][4]. All arithmetic identical to round 19 -> absmax unchanged.
// ---------------------------------------------------------------------------
#define BUFS 16384   // shorts per staging buffer (32 KB)

// phase-1 stage: 24 insts (3/wave): A 2 groups x 32 rows @ [0,2048),
// B (Wt) 256 rows @ [2048,10240), dup A @ [10240,12288).
__device__ __forceinline__ void st_p1(short* dst,
                                      const short* gA0, const short* gA1,
                                      const short* gB, int wave, int lane, int k0) {
#pragma unroll
  for (int j = 0; j < 3; ++j) {
    int inst = wave * 3 + j;               // 0..23
    if (inst < 4 || inst >= 20) {          // A (and dup copy of A)
      int ai = (inst < 4) ? inst : (inst - 20);     // 0..3
      const short* src = (ai < 2) ? gA0 : gA1;
      int lr = (ai & 1) * 16 + (lane >> 2);         // 0..31 local row
      int gc = (lane & 3) ^ ((lr >> 1) & 3);
      int toff = ((inst < 4) ? 0 : 10240) + ai * 512;
      GLDS16(src + (size_t)lr * SSZ + k0 + gc * 8, dst + toff);
    } else {                               // B rows
      int bi = inst - 4;                   // 0..15
      int brow = bi * 16 + (lane >> 2);    // 0..255
      int gc = (lane & 3) ^ ((brow >> 1) & 3);
      GLDS16(gB + (size_t)brow * SSZ + k0 + gc * 8, dst + 2048 + bi * 512);
    }
  }
}
// phase-2/3 stage: 32 insts (4/wave): B_g0 @ [0,8192), B_g1 @ [8192,16384).
__device__ __forceinline__ void st_p23(short* dst,
                                       const short* gB0, const short* gB1,
                                       int ld, int wave, int lane, int k0) {
#pragma unroll
  for (int j = 0; j < 4; ++j) {
    int inst = wave * 4 + j;               // 0..31
    int g = inst >> 4;
    int r16 = inst & 15;
    int brow = r16 * 16 + (lane >> 2);     // 0..255
    int gc = (lane & 3) ^ ((brow >> 1) & 3);
    const short* src = g ? gB1 : gB0;
    GLDS16(src + (size_t)brow * ld + k0 + gc * 8, dst + g * 8192 + r16 * 512);
  }
}

__global__ __launch_bounds__(512) void k123(const unsigned short* __restrict__ wc16,
                                            const unsigned short* __restrict__ Wt16,
                                            const unsigned short* __restrict__ cT16,
                                            const unsigned short* __restrict__ ctx16,
                                            unsigned short* __restrict__ P16,
                                            unsigned short* __restrict__ N216) {
  __shared__ __align__(16) short S[3 * BUFS + 16384];   // 128 KB
  short* P_lds = &S[3 * BUFS];                           // 2 groups x 32x256 fp16

  int blk = blockIdx.x;
  int h = blk & 7, ih = (blk >> 3) & 1, bp = blk >> 4;
  int ibase = ih * 32;
  int t = threadIdx.x;
  int lane = t & 63, wave = t >> 6;             // 0..7
  int g = wave >> 2, w4 = wave & 3;             // group, wave-in-group
  int ln15 = lane & 15, kh = lane >> 4;
  int rowq = (lane >> 4) * 4;

  int b_g = bp * 2 + g;
  int bh_g = b_g * 8 + h;

  const short* gA0 = (const short*)wc16 + (size_t)((bp * 2 + 0) * IDF + ibase) * SSZ;
  const short* gA1 = (const short*)wc16 + (size_t)((bp * 2 + 1) * IDF + ibase) * SSZ;
  const short* gB  = (const short*)Wt16 + (size_t)h * CDF * SSZ;
  const short* gT0 = (const short*)cT16 + (size_t)(bp * 2 + 0) * LL * CDF;
  const short* gT1 = (const short*)cT16 + (size_t)(bp * 2 + 1) * LL * CDF;
  const short* gC0 = (const short*)ctx16 + (size_t)(bp * 2 + 0) * CDF * LL;
  const short* gC1 = (const short*)ctx16 + (size_t)(bp * 2 + 1) * CDF * LL;

  // phase-1 A frag offsets (A region: group g rows at g*1024)
  int offA[2], rowM[2], rmask[2];
#pragma unroll
  for (int r = 0; r < 2; ++r) {
    int lr = r * 16 + ln15;                    // 0..31 local row
    offA[r] = g * 1024 + lr * 32 + ((kh ^ ((lr >> 1) & 3)) * 8);
    rowM[r] = g * 8192 + lr * 256;             // P_lds row base
    rmask[r] = lr & 7;
  }
  // B frag offsets: phase 1 (shared Wt @2048) and phase 2/3 (per-group @g*8192)
  int offB1[4], offB2[4];
#pragma unroll
  for (int c = 0; c < 4; ++c) {
    int row = w4 * 64 + c * 16 + ln15;         // 0..255
    int swz = ((kh ^ ((row >> 1) & 3)) * 8);
    offB1[c] = 2048 + row * 32 + swz;
    offB2[c] = g * 8192 + row * 32 + swz;
  }

  f32x4 acc[2][4] = {};

  // ===== Phase 1: M = wc x Wt^T, K=1024 =====
  st_p1(&S[0],        gA0, gA1, gB, wave, lane, 0);
  st_p1(&S[BUFS],     gA0, gA1, gB, wave, lane, 32);
  st_p1(&S[2 * BUFS], gA0, gA1, gB, wave, lane, 64);
  int cur = 0;
  {
    const int NSTEP = 32;
#pragma unroll 1
    for (int ks = 0; ks < NSTEP; ++ks) {
      short* Sc = &S[cur * BUFS];
      WAIT_ENTER3(6, 3)
      half8v fa[2], fb[4];
#pragma unroll
      for (int r = 0; r < 2; ++r)
        fa[r] = *reinterpret_cast<const half8v*>(&Sc[offA[r]]);
#pragma unroll
      for (int c = 0; c < 4; ++c)
        fb[c] = *reinterpret_cast<const half8v*>(&Sc[offB1[c]]);
      __builtin_amdgcn_s_setprio(1);
#pragma unroll
      for (int r = 0; r < 2; ++r)
#pragma unroll
        for (int c = 0; c < 4; ++c)
          acc[r][c] = __builtin_amdgcn_mfma_f32_16x16x32_f16(fa[r], fb[c], acc[r][c], 0, 0, 0);
      __builtin_amdgcn_s_setprio(0);
      BAR_EXIT()
      if (ks + 3 < NSTEP)
        st_p1(Sc, gA0, gA1, gB, wave, lane, (ks + 3) * 32);
      cur = (cur == 2) ? 0 : cur + 1;
    }
  }
  // M -> P_lds (fp16, chunk-XOR(row&7)), group region
#pragma unroll
  for (int r = 0; r < 2; ++r)
#pragma unroll
    for (int c = 0; c < 4; ++c)
#pragma unroll
      for (int reg = 0; reg < 4; ++reg) {
        int row = r * 16 + rowq + reg;         // 0..31 local
        int col = w4 * 64 + c * 16 + ln15;     // 0..255
        P_lds[g * 8192 + row * 256 +
              ((((col >> 3) ^ (row & 7)) << 3) + (col & 7))] =
            (short)f2h(acc[r][c][reg]);
      }
  LDS_BAR()

  // ===== Phase 2: logits = M_lds x cT[b_g]^T, K=256 =====
#pragma unroll
  for (int r = 0; r < 2; ++r)
#pragma unroll
    for (int c = 0; c < 4; ++c) acc[r][c] = (f32x4){0.f, 0.f, 0.f, 0.f};
  st_p23(&S[0],        gT0, gT1, CDF, wave, lane, 0);
  st_p23(&S[BUFS],     gT0, gT1, CDF, wave, lane, 32);
  st_p23(&S[2 * BUFS], gT0, gT1, CDF, wave, lane, 64);
  cur = 0;
  {
    const int NSTEP = 8;
#pragma unroll 1
    for (int ks = 0; ks < NSTEP; ++ks) {
      short* Sc = &S[cur * BUFS];
      WAIT_ENTER3(8, 4)
      half8v fa[2], fb[4];
#pragma unroll
      for (int r = 0; r < 2; ++r) {
        int ck = ((ks * 4 + kh) ^ rmask[r]) << 3;
        fa[r] = *reinterpret_cast<const half8v*>(&P_lds[rowM[r] + ck]);
      }
#pragma unroll
      for (int c = 0; c < 4; ++c)
        fb[c] = *reinterpret_cast<const half8v*>(&Sc[offB2[c]]);
      __builtin_amdgcn_s_setprio(1);
#pragma unroll
      for (int r = 0; r < 2; ++r)
#pragma unroll
        for (int c = 0; c < 4; ++c)
          acc[r][c] = __builtin_amdgcn_mfma_f32_16x16x32_f16(fa[r], fb[c], acc[r][c], 0, 0, 0);
      __builtin_amdgcn_s_setprio(0);
      BAR_EXIT()
      if (ks + 3 < NSTEP)
        st_p23(Sc, gT0, gT1, CDF, wave, lane, (ks + 3) * 32);
      cur = (cur == 2) ? 0 : cur + 1;
    }
  }

  // Prefetch phase-3 B (ctx16) BEFORE softmax; stays in flight (LDS_BAR only).
  st_p23(&S[0],        gC0, gC1, LL, wave, lane, 0);
  st_p23(&S[BUFS],     gC0, gC1, LL, wave, lane, 32);
  st_p23(&S[2 * BUFS], gC0, gC1, LL, wave, lane, 64);

  // ===== Softmax over l (cols), per group. pm in group's P_lds region. =====
  float* pm = reinterpret_cast<float*>(&P_lds[g * 8192]);   // 32 rows x 4 floats
  float gmax[2][4], ginv[2][4];
#pragma unroll
  for (int r = 0; r < 2; ++r)
#pragma unroll
    for (int reg = 0; reg < 4; ++reg) {
      float m = fmaxf(fmaxf(acc[r][0][reg], acc[r][1][reg]),
                      fmaxf(acc[r][2][reg], acc[r][3][reg]));
#pragma unroll
      for (int msk = 8; msk >= 1; msk >>= 1) m = fmaxf(m, __shfl_xor(m, msk, 64));
      if (ln15 == 0) pm[(r * 16 + rowq + reg) * 4 + w4] = m;
    }
  LDS_BAR()
#pragma unroll
  for (int r = 0; r < 2; ++r)
#pragma unroll
    for (int reg = 0; reg < 4; ++reg) {
      int row = r * 16 + rowq + reg;
      float4 p0 = *reinterpret_cast<const float4*>(&pm[row * 4]);
      gmax[r][reg] = fmaxf(fmaxf(p0.x, p0.y), fmaxf(p0.z, p0.w));
    }
  LDS_BAR()
#pragma unroll
  for (int r = 0; r < 2; ++r)
#pragma unroll
    for (int reg = 0; reg < 4; ++reg) {
      float s = 0.f;
#pragma unroll
      for (int c = 0; c < 4; ++c) {
        acc[r][c][reg] = __expf(acc[r][c][reg] - gmax[r][reg]);
        s += acc[r][c][reg];
      }
#pragma unroll
      for (int msk = 8; msk >= 1; msk >>= 1) s += __shfl_xor(s, msk, 64);
      if (ln15 == 0) pm[(r * 16 + rowq + reg) * 4 + w4] = s;
    }
  LDS_BAR()
#pragma unroll
  for (int r = 0; r < 2; ++r)
#pragma unroll
    for (int reg = 0; reg < 4; ++reg) {
      int row = r * 16 + rowq + reg;
      float4 p0 = *reinterpret_cast<const float4*>(&pm[row * 4]);
      ginv[r][reg] = 1.f / (p0.x + p0.y + p0.z + p0.w);
    }
  LDS_BAR()   // pm fully consumed before P overwrites the region

  // P -> global (for epilogue) and -> P_lds (phase-3 A operand)
  size_t pbase = (size_t)bh_g * IDF * LL + (size_t)ibase * LL;
#pragma unroll
  for (int r = 0; r < 2; ++r)
#pragma unroll
    for (int c = 0; c < 4; ++c)
#pragma unroll
      for (int reg = 0; reg < 4; ++reg) {
        float p = acc[r][c][reg] * ginv[r][reg];
        int row = r * 16 + rowq + reg;
        int col = w4 * 64 + c * 16 + ln15;
        unsigned short ph = f2h(p);
        P16[pbase + (size_t)row * LL + col] = ph;
        P_lds[g * 8192 + row * 256 +
              ((((col >> 3) ^ (row & 7)) << 3) + (col & 7))] = (short)ph;
      }
  LDS_BAR()

  // ===== Phase 3: N2 = P_lds x ctx[b_g]^T, K=256 =====
#pragma unroll
  for (int r = 0; r < 2; ++r)
#pragma unroll
    for (int c = 0; c < 4; ++c) acc[r][c] = (f32x4){0.f, 0.f, 0.f, 0.f};
  cur = 0;
  {
    const int NSTEP = 8;
#pragma unroll 1
    for (int ks = 0; ks < NSTEP; ++ks) {
      short* Sc = &S[cur * BUFS];
      WAIT_ENTER3(8, 4)
      half8v fa[2], fb[4];
#pragma unroll
      for (int r = 0; r < 2; ++r) {
        int ck = ((ks * 4 + kh) ^ rmask[r]) << 3;
        fa[r] = *reinterpret_cast<const half8v*>(&P_lds[rowM[r] + ck]);
      }
#pragma unroll
      for (int c = 0; c < 4; ++c)
        fb[c] = *reinterpret_cast<const half8v*>(&Sc[offB2[c]]);
      __builtin_amdgcn_s_setprio(1);
#pragma unroll
      for (int r = 0; r < 2; ++r)
#pragma unroll
        for (int c = 0; c < 4; ++c)
          acc[r][c] = __builtin_amdgcn_mfma_f32_16x16x32_f16(fa[r], fb[c], acc[r][c], 0, 0, 0);
      __builtin_amdgcn_s_setprio(0);
      BAR_EXIT()
      if (ks + 3 < NSTEP)
        st_p23(Sc, gC0, gC1, LL, wave, lane, (ks + 3) * 32);
      cur = (cur == 2) ? 0 : cur + 1;
    }
  }

  size_t nbase = (size_t)b_g * IDF * KHC + (size_t)ibase * KHC + h * CDF;
#pragma unroll
  for (int r = 0; r < 2; ++r)
#pragma unroll
    for (int c = 0; c < 4; ++c)
#pragma unroll
      for (int reg = 0; reg < 4; ++reg) {
        int row = r * 16 + rowq + reg;
        int col = w4 * 64 + c * 16 + ln15;
        N216[nbase + (size_t)row * KHC + col] = f2h(acc[r][c][reg]);
      }
}

// ---------------------------------------------------------------------------
// K4 (MFMA fp16, 3-deep): ctx_out[b][i][o] = sum_{hc} N2*W. UNCHANGED.
// ---------------------------------------------------------------------------
__device__ __forceinline__ void k4_stage(short* dst,
                                         const short* gA, const short* gB,
                                         int wave, int lane, int kk0, int obase) {
  int h4 = kk0 >> 8, cb = kk0 & 255;
#pragma unroll
  for (int j = 0; j < 3; ++j) {
    int inst = wave * 3 + j;               // 0..11
    if (inst < 4) {
      int rb = inst * 16;
      int r  = rb + (lane >> 2);
      int gc = (lane & 3) ^ ((r >> 1) & 3);
      GLDS16(gA + (size_t)r * KHC + kk0 + gc * 8, dst + rb * 32);
    } else {
      int rb = (inst - 4) * 16;
      int r  = rb + (lane >> 2);
      int gc = (lane & 3) ^ ((r >> 1) & 3);
      GLDS16(gB + (size_t)(h4 * SSZ + obase + r) * CDF + cb + gc * 8,
             dst + 2048 + rb * 32);
    }
  }
}

__global__ __launch_bounds__(256) void k4_mfma(const unsigned short* __restrict__ N216,
                                               const unsigned short* __restrict__ W16,
                                               float* __restrict__ out0,
                                               float* __restrict__ out1) {
  __shared__ __align__(16) short S[3 * 6144];   // 36 KB

  int blk = blockIdx.x;
  int g = blk >> 8;
  int r8 = blk & 255;
  int b = r8 >> 3, ot = r8 & 7;
  int obase = ot * 128;
  int t = threadIdx.x;
  int lane = t & 63, wave = t >> 6;
  int ln15 = lane & 15, kh = lane >> 4;

  const short* gA = (const short*)N216 + (size_t)b * IDF * KHC;
  const short* gB = (const short*)W16;

  int offA[4], offB[2];
#pragma unroll
  for (int r = 0; r < 4; ++r) {
    int row = r * 16 + ln15;
    offA[r] = row * 32 + ((kh ^ ((row >> 1) & 3)) * 8);
  }
#pragma unroll
  for (int c = 0; c < 2; ++c) {
    int row = wave * 32 + c * 16 + ln15;
    offB[c] = 2048 + row * 32 + ((kh ^ ((row >> 1) & 3)) * 8);
  }

  int kbase = g * (KHC / 2);
  f32x4 acc[4][2] = {};

  k4_stage(&S[0],        gA, gB, wave, lane, kbase, obase);
  k4_stage(&S[6144],     gA, gB, wave, lane, kbase + 32, obase);
  k4_stage(&S[2 * 6144], gA, gB, wave, lane, kbase + 64, obase);
  int cur = 0;

  const int NSTEP = 32;
#pragma unroll 1
  for (int ks = 0; ks < NSTEP; ++ks) {
    short* Sc = &S[cur * 6144];
    WAIT_ENTER3(6, 3)
    half8v fa[4], fb[2];
#pragma unroll
    for (int r = 0; r < 4; ++r)
      fa[r] = *reinterpret_cast<const half8v*>(&Sc[offA[r]]);
#pragma unroll
    for (int c = 0; c < 2; ++c)
      fb[c] = *reinterpret_cast<const half8v*>(&Sc[offB[c]]);
    __builtin_amdgcn_s_setprio(1);
#pragma unroll
    for (int r = 0; r < 4; ++r)
#pragma unroll
      for (int c = 0; c < 2; ++c)
        acc[r][c] = __builtin_amdgcn_mfma_f32_16x16x32_f16(fa[r], fb[c], acc[r][c], 0, 0, 0);
    __builtin_amdgcn_s_setprio(0);
    BAR_EXIT()
    if (ks + 3 < NSTEP)
      k4_stage(Sc, gA, gB, wave, lane, kbase + (ks + 3) * 32, obase);
    cur = (cur == 2) ? 0 : cur + 1;
  }

  float* dst = (g == 0) ? out0 : out1;
  int rowq = (lane >> 4) * 4;
#pragma unroll
  for (int r = 0; r < 4; ++r)
#pragma unroll
    for (int c = 0; c < 2; ++c)
#pragma unroll
      for (int reg = 0; reg < 4; ++reg)
        dst[((size_t)b * IDF + r * 16 + rowq + reg) * SSZ +
            obase + wave * 32 + c * 16 + ln15] = acc[r][c][reg];
}

// ---------------------------------------------------------------------------
// Fused epilogue: blocks 0..127 -> attn_out[b][l][i] = sum_h P16[bh][i][l];
// blocks 128..2175 -> out[idx] += Pbuf[idx] (k4 g=1 partial).
// ---------------------------------------------------------------------------
__global__ __launch_bounds__(256) void k_epi(const unsigned short* __restrict__ P16,
                                             float* __restrict__ outa,
                                             float* __restrict__ out,
                                             const float* __restrict__ Pbuf) {
  int blk0 = blockIdx.x;
  int tid = threadIdx.x;
  if (blk0 >= 128) {                       // out += Pbuf
    int idx = (blk0 - 128) * 256 + tid;
    float4 a = reinterpret_cast<float4*>(out)[idx];
    float4 p = reinterpret_cast<const float4*>(Pbuf)[idx];
    a.x += p.x; a.y += p.y; a.z += p.z; a.w += p.w;
    reinterpret_cast<float4*>(out)[idx] = a;
    return;
  }
  __shared__ float T[64][65];
  int b = blk0 >> 2, lt = blk0 & 3;
  int l0 = lt * 64;
  float4 acc[4];
#pragma unroll
  for (int p = 0; p < 4; ++p) acc[p] = make_float4(0.f, 0.f, 0.f, 0.f);
  for (int h = 0; h < NH; ++h) {
    size_t src = (size_t)(b * NH + h) * IDF * LL;
#pragma unroll
    for (int p = 0; p < 4; ++p) {
      int f = tid + p * 256;
      int i = f >> 4, lc = (f & 15) * 4;
      ushort4 u = *reinterpret_cast<const ushort4*>(&P16[src + i * LL + l0 + lc]);
      acc[p].x += h2f(u.x); acc[p].y += h2f(u.y);
      acc[p].z += h2f(u.z); acc[p].w += h2f(u.w);
    }
  }
#pragma unroll
  for (int p = 0; p < 4; ++p) {
    int f = tid + p * 256;
    int i = f >> 4, lc = (f & 15) * 4;
    T[i][lc + 0] = acc[p].x; T[i][lc + 1] = acc[p].y;
    T[i][lc + 2] = acc[p].z; T[i][lc + 3] = acc[p].w;
  }
  __syncthreads();
#pragma unroll
  for (int p = 0; p < 4; ++p) {
    int f = tid + p * 256;
    int lr = f >> 4, ic = (f & 15) * 4;
    float4 v = {T[ic + 0][lr], T[ic + 1][lr], T[ic + 2][lr], T[ic + 3][lr]};
    *reinterpret_cast<float4*>(&outa[((size_t)b * LL + l0 + lr) * IDF + ic]) = v;
  }
}

// ---------------------------------------------------------------------------
extern "C" void kernel_launch(void* const* d_in, const int* in_sizes, int n_in,
                              void* d_out, int out_size, void* d_ws, size_t ws_size,
                              hipStream_t stream) {
  const float* wc  = (const float*)d_in[0];   // [32][64][1024]
  const float* ctx = (const float*)d_in[1];   // [32][256][256]
  const float* W   = (const float*)d_in[2];   // [8][1024][256]
  float* out = (float*)d_out;

  const size_t NE = 2097152;   // elems of wc == W == ctx
  const size_t NM = 4194304;   // elems of P == N2
  unsigned short* p = (unsigned short*)d_ws;
  unsigned short *wc16 = p;   p += NE;
  unsigned short *Wt16 = p;   p += NE;
  unsigned short *W16  = p;   p += NE;
  unsigned short *ctx16 = p;  p += NE;
  unsigned short *cT16 = p;   p += NE;
  unsigned short *P16  = p;   p += NM;
  unsigned short *N216 = p;   p += NM;
  float* Pbuf = (float*)p;    // 2.1M floats

  k_prep  <<<7168, 256, 0, stream>>>(wc, W, ctx, wc16, W16, ctx16, Wt16, cT16);
  k123    <<<256, 512, 0, stream>>>(wc16, Wt16, cT16, ctx16, P16, N216);
  k4_mfma <<<512, 256, 0, stream>>>(N216, W16, out, Pbuf);
  k_epi   <<<2176, 256, 0, stream>>>(P16, out + (size_t)BB * IDF * SSZ, out, Pbuf);
}

// Round 21
// 76.185 us; speedup vs baseline: 1.0796x; 1.0266x over previous
//
#include <hip/hip_runtime.h>
#include <hip/hip_bf16.h>

#define BB 32
#define IDF 64
#define CDF 256
#define SSZ 1024
#define NH 8
#define LL 256
#define KHC 2048   // NH*CDF

typedef __attribute__((ext_vector_type(8))) _Float16 half8v;   // 8 fp16
typedef __attribute__((ext_vector_type(4))) float f32x4;       // MFMA acc

// async global->LDS, 16B per lane, LDS dest = wave-uniform base + lane*16
#define GLDS16(g, l) __builtin_amdgcn_global_load_lds(                        \
    (const __attribute__((address_space(1))) void*)(g),                       \
    (__attribute__((address_space(3))) void*)(l), 16, 0, 0)

// 3-deep pipeline phase entry (T3+T4): wait only for the CURRENT buffer's
// DMA, leaving the next TWO stages in flight. Never vmcnt(0) mid-loop.
#define WAIT_ENTER3(NFULL, NHALF)                                             \
  { if (ks < NSTEP - 2)                                                       \
      asm volatile("s_waitcnt vmcnt(" #NFULL ")" ::: "memory");               \
    else if (ks == NSTEP - 2)                                                 \
      asm volatile("s_waitcnt vmcnt(" #NHALF ")" ::: "memory");               \
    else                                                                      \
      asm volatile("s_waitcnt vmcnt(0)" ::: "memory");                        \
    __builtin_amdgcn_s_barrier();                                             \
    __builtin_amdgcn_sched_barrier(0); }
#define BAR_EXIT()                                                            \
  { __builtin_amdgcn_sched_barrier(0);                                        \
    __builtin_amdgcn_s_barrier();                                             \
    __builtin_amdgcn_sched_barrier(0); }
// LDS-only barrier: drains ds ops but leaves global_load_lds (vmcnt) in
// flight — lets phase-3 prefetch ride through the softmax.
#define LDS_BAR()                                                             \
  { asm volatile("s_waitcnt lgkmcnt(0)" ::: "memory");                        \
    __builtin_amdgcn_s_barrier();                                             \
    __builtin_amdgcn_sched_barrier(0); }

__device__ inline unsigned short f2h(float x) {
  _Float16 h = (_Float16)x;
  return *reinterpret_cast<unsigned short*>(&h);
}
__device__ inline float h2f(unsigned short u) {
  _Float16 h = *reinterpret_cast<_Float16*>(&u);
  return (float)h;
}

// ---------------------------------------------------------------------------
// Fused prep: blocks 0..6143 elementwise casts (wc,W,ctx -> fp16);
// blocks 6144..6655 -> Wt16 [h][c][o]; 6656..7167 -> cT16 [b][l][c].
// ---------------------------------------------------------------------------
__global__ __launch_bounds__(256) void k_prep(const float* __restrict__ wc,
                                              const float* __restrict__ W,
                                              const float* __restrict__ ctx,
                                              unsigned short* __restrict__ wc16,
                                              unsigned short* __restrict__ W16,
                                              unsigned short* __restrict__ ctx16,
                                              unsigned short* __restrict__ Wt16,
                                              unsigned short* __restrict__ cT16) {
  __shared__ float Tt[64][65];
  int blk0 = blockIdx.x;
  int t = threadIdx.x;
  if (blk0 < 6144) {                       // elementwise casts
    int sel = blk0 >> 11;
    int idx = ((blk0 & 2047) * 256 + t) * 4;
    const float* src = (sel == 0) ? wc : (sel == 1) ? W : ctx;
    unsigned short* d = (sel == 0) ? wc16 : (sel == 1) ? W16 : ctx16;
    float4 v = *reinterpret_cast<const float4*>(&src[idx]);
    __align__(8) unsigned short h[4] = {f2h(v.x), f2h(v.y), f2h(v.z), f2h(v.w)};
    *reinterpret_cast<int2*>(&d[idx]) = *reinterpret_cast<int2*>(h);
  } else if (blk0 < 6656) {                // W -> Wt16 [h][c][o]
    int blk = blk0 - 6144;
    int h = blk >> 6, ot = (blk >> 2) & 15, cq = blk & 3;
    int og = ot * 64, cg = cq * 64;
    int o_l = t >> 4, c4 = (t & 15) * 4;
#pragma unroll
    for (int p = 0; p < 4; ++p) {
      int o = o_l + 16 * p;
      float4 v = *reinterpret_cast<const float4*>(
          &W[((size_t)h * SSZ + og + o) * CDF + cg + c4]);
      Tt[c4 + 0][o] = v.x; Tt[c4 + 1][o] = v.y;
      Tt[c4 + 2][o] = v.z; Tt[c4 + 3][o] = v.w;
    }
    __syncthreads();
    int c_l = t >> 2;
#pragma unroll
    for (int p = 0; p < 4; ++p) {
      int o0 = ((t & 3) + 4 * p) * 4;
      __align__(8) unsigned short hv[4];
#pragma unroll
      for (int j = 0; j < 4; ++j) hv[j] = f2h(Tt[c_l][o0 + j]);
      size_t base = ((size_t)h * CDF + cg + c_l) * SSZ + og + o0;
      *reinterpret_cast<int2*>(&Wt16[base]) = *reinterpret_cast<int2*>(hv);
    }
  } else {                                 // ctx -> cT16 [b][l][c]
    int blk = blk0 - 6656;
    int b = blk >> 4, cq = (blk >> 2) & 3, lt = blk & 3;
    int cg = cq * 64, lg = lt * 64;
    int c_l = t >> 4, l4 = (t & 15) * 4;
#pragma unroll
    for (int p = 0; p < 4; ++p) {
      int c = c_l + 16 * p;
      float4 v = *reinterpret_cast<const float4*>(
          &ctx[((size_t)b * CDF + cg + c) * LL + lg + l4]);
      Tt[l4 + 0][c] = v.x; Tt[l4 + 1][c] = v.y;
      Tt[l4 + 2][c] = v.z; Tt[l4 + 3][c] = v.w;
    }
    __syncthreads();
    int l_l = t >> 2;
#pragma unroll
    for (int p = 0; p < 4; ++p) {
      int c0 = ((t & 3) + 4 * p) * 4;
      __align__(8) unsigned short hv[4];
#pragma unroll
      for (int j = 0; j < 4; ++j) hv[j] = f2h(Tt[l_l][c0 + j]);
      size_t base = ((size_t)b * LL + lg + l_l) * CDF + cg + c0;
      *reinterpret_cast<int2*>(&cT16[base]) = *reinterpret_cast<int2*>(hv);
    }
  }
}

// ---------------------------------------------------------------------------
// k123: fused K1+K2+K3, block = (b,h), 512 thr = 8 waves = 2 groups by
// ROW-HALF (ih). This shares BOTH B-panels: phase 1 stages Wt[h] once
// (24 insts/step incl. dup) AND phases 2/3 stage cT[b]/ctx[b] once
// (16 insts/step vs round-20's 32 — the p2/p3 DMA rate halves).
// Group g computes rows [g*32, g*32+32) of (b,h); softmax is over cols,
// rows independent -> per-group reduce unchanged.
// LDS: 3 x 24KB staging + 32KB M/P_lds (64x256 fp16) = 104 KB.
// ---------------------------------------------------------------------------
#define BUFS 12288   // shorts per staging buffer (24 KB)

// phase-1 stage, 24 insts (3/wave): A wc[b] 64 rows @ [0,2048),
// B Wt[h] 256 rows @ [2048,10240), dup A @ [10240,12288).
__device__ __forceinline__ void st_p1(short* dst, const short* gA, const short* gB,
                                      int wave, int lane, int k0) {
#pragma unroll
  for (int j = 0; j < 3; ++j) {
    int inst = wave * 3 + j;               // 0..23
    if (inst < 4 || inst >= 20) {          // A (and dup copy)
      int ai = (inst < 4) ? inst : (inst - 20);     // 0..3
      int r  = ai * 16 + (lane >> 2);                // 0..63
      int gc = (lane & 3) ^ ((r >> 1) & 3);
      int toff = ((inst < 4) ? 0 : 10240) + ai * 512;
      GLDS16(gA + (size_t)r * SSZ + k0 + gc * 8, dst + toff);
    } else {                               // B rows
      int bi = inst - 4;                   // 0..15
      int brow = bi * 16 + (lane >> 2);    // 0..255
      int gc = (lane & 3) ^ ((brow >> 1) & 3);
      GLDS16(gB + (size_t)brow * SSZ + k0 + gc * 8, dst + 2048 + bi * 512);
    }
  }
}
// phase-2/3 stage, 16 insts (2/wave): shared B panel 256 rows @ [0,8192).
__device__ __forceinline__ void st_p23(short* dst, const short* gB, int ld,
                                       int wave, int lane, int k0) {
#pragma unroll
  for (int j = 0; j < 2; ++j) {
    int inst = wave * 2 + j;               // 0..15
    int brow = inst * 16 + (lane >> 2);    // 0..255
    int gc = (lane & 3) ^ ((brow >> 1) & 3);
    GLDS16(gB + (size_t)brow * ld + k0 + gc * 8, dst + inst * 512);
  }
}

__global__ __launch_bounds__(512) void k123(const unsigned short* __restrict__ wc16,
                                            const unsigned short* __restrict__ Wt16,
                                            const unsigned short* __restrict__ cT16,
                                            const unsigned short* __restrict__ ctx16,
                                            unsigned short* __restrict__ P16,
                                            unsigned short* __restrict__ N216) {
  __shared__ __align__(16) short S[3 * BUFS + 16384];   // 104 KB
  short* P_lds = &S[3 * BUFS];                           // 64 x 256 fp16

  int blk = blockIdx.x;                    // = bh
  int b = blk >> 3, h = blk & 7;
  int t = threadIdx.x;
  int lane = t & 63, wave = t >> 6;             // 0..7
  int g = wave >> 2, w4 = wave & 3;             // row-half group, wave-in-group
  int ln15 = lane & 15, kh = lane >> 4;
  int rowq = (lane >> 4) * 4;

  const short* gA = (const short*)wc16 + (size_t)b * IDF * SSZ;
  const short* gB = (const short*)Wt16 + (size_t)h * CDF * SSZ;
  const short* gT = (const short*)cT16 + (size_t)b * LL * CDF;
  const short* gC = (const short*)ctx16 + (size_t)b * CDF * LL;

  // A frag offsets: group g's rows = g*32 + r*16 + ln15 (global 0..63)
  int offA[2], rowM[2], rmask[2], grow[2];
#pragma unroll
  for (int r = 0; r < 2; ++r) {
    int row = g * 32 + r * 16 + ln15;          // 0..63
    grow[r] = row;
    offA[r] = row * 32 + ((kh ^ ((row >> 1) & 3)) * 8);
    rowM[r] = row * 256;
    rmask[r] = row & 7;
  }
  // B frag offsets: phase 1 (Wt @2048) and phases 2/3 (shared panel @0)
  int offB1[4], offB2[4];
#pragma unroll
  for (int c = 0; c < 4; ++c) {
    int row = w4 * 64 + c * 16 + ln15;         // 0..255
    int swz = ((kh ^ ((row >> 1) & 3)) * 8);
    offB1[c] = 2048 + row * 32 + swz;
    offB2[c] = row * 32 + swz;
  }

  f32x4 acc[2][4] = {};

  // ===== Phase 1: M = wc x Wt^T, K=1024 =====
  st_p1(&S[0],        gA, gB, wave, lane, 0);
  st_p1(&S[BUFS],     gA, gB, wave, lane, 32);
  st_p1(&S[2 * BUFS], gA, gB, wave, lane, 64);
  int cur = 0;
  {
    const int NSTEP = 32;
#pragma unroll 1
    for (int ks = 0; ks < NSTEP; ++ks) {
      short* Sc = &S[cur * BUFS];
      WAIT_ENTER3(6, 3)
      half8v fa[2], fb[4];
#pragma unroll
      for (int r = 0; r < 2; ++r)
        fa[r] = *reinterpret_cast<const half8v*>(&Sc[offA[r]]);
#pragma unroll
      for (int c = 0; c < 4; ++c)
        fb[c] = *reinterpret_cast<const half8v*>(&Sc[offB1[c]]);
      __builtin_amdgcn_s_setprio(1);
#pragma unroll
      for (int r = 0; r < 2; ++r)
#pragma unroll
        for (int c = 0; c < 4; ++c)
          acc[r][c] = __builtin_amdgcn_mfma_f32_16x16x32_f16(fa[r], fb[c], acc[r][c], 0, 0, 0);
      __builtin_amdgcn_s_setprio(0);
      BAR_EXIT()
      if (ks + 3 < NSTEP)
        st_p1(Sc, gA, gB, wave, lane, (ks + 3) * 32);
      cur = (cur == 2) ? 0 : cur + 1;
    }
  }
  // M -> P_lds (fp16, chunk-XOR(row&7))
#pragma unroll
  for (int r = 0; r < 2; ++r)
#pragma unroll
    for (int c = 0; c < 4; ++c)
#pragma unroll
      for (int reg = 0; reg < 4; ++reg) {
        int row = g * 32 + r * 16 + rowq + reg;   // 0..63
        int col = w4 * 64 + c * 16 + ln15;        // 0..255
        P_lds[row * 256 + ((((col >> 3) ^ (row & 7)) << 3) + (col & 7))] =
            (short)f2h(acc[r][c][reg]);
      }
  LDS_BAR()

  // ===== Phase 2: logits = M_lds x cT[b]^T, K=256 (shared B) =====
#pragma unroll
  for (int r = 0; r < 2; ++r)
#pragma unroll
    for (int c = 0; c < 4; ++c) acc[r][c] = (f32x4){0.f, 0.f, 0.f, 0.f};
  st_p23(&S[0],        gT, CDF, wave, lane, 0);
  st_p23(&S[BUFS],     gT, CDF, wave, lane, 32);
  st_p23(&S[2 * BUFS], gT, CDF, wave, lane, 64);
  cur = 0;
  {
    const int NSTEP = 8;
#pragma unroll 1
    for (int ks = 0; ks < NSTEP; ++ks) {
      short* Sc = &S[cur * BUFS];
      WAIT_ENTER3(4, 2)
      half8v fa[2], fb[4];
#pragma unroll
      for (int r = 0; r < 2; ++r) {
        int ck = ((ks * 4 + kh) ^ rmask[r]) << 3;
        fa[r] = *reinterpret_cast<const half8v*>(&P_lds[rowM[r] + ck]);
      }
#pragma unroll
      for (int c = 0; c < 4; ++c)
        fb[c] = *reinterpret_cast<const half8v*>(&Sc[offB2[c]]);
      __builtin_amdgcn_s_setprio(1);
#pragma unroll
      for (int r = 0; r < 2; ++r)
#pragma unroll
        for (int c = 0; c < 4; ++c)
          acc[r][c] = __builtin_amdgcn_mfma_f32_16x16x32_f16(fa[r], fb[c], acc[r][c], 0, 0, 0);
      __builtin_amdgcn_s_setprio(0);
      BAR_EXIT()
      if (ks + 3 < NSTEP)
        st_p23(Sc, gT, CDF, wave, lane, (ks + 3) * 32);
      cur = (cur == 2) ? 0 : cur + 1;
    }
  }

  // Prefetch phase-3 B (ctx16) BEFORE softmax; stays in flight (LDS_BAR only).
  st_p23(&S[0],        gC, LL, wave, lane, 0);
  st_p23(&S[BUFS],     gC, LL, wave, lane, 32);
  st_p23(&S[2 * BUFS], gC, LL, wave, lane, 64);

  // ===== Softmax over l (cols). pm overlays first 4 KB of P_lds (M dead). =====
  float* pm = reinterpret_cast<float*>(P_lds);   // 64 rows x 4 floats
  float gmax[2][4], ginv[2][4];
#pragma unroll
  for (int r = 0; r < 2; ++r)
#pragma unroll
    for (int reg = 0; reg < 4; ++reg) {
      float m = fmaxf(fmaxf(acc[r][0][reg], acc[r][1][reg]),
                      fmaxf(acc[r][2][reg], acc[r][3][reg]));
#pragma unroll
      for (int msk = 8; msk >= 1; msk >>= 1) m = fmaxf(m, __shfl_xor(m, msk, 64));
      if (ln15 == 0) pm[(g * 32 + r * 16 + rowq + reg) * 4 + w4] = m;
    }
  LDS_BAR()
#pragma unroll
  for (int r = 0; r < 2; ++r)
#pragma unroll
    for (int reg = 0; reg < 4; ++reg) {
      int row = g * 32 + r * 16 + rowq + reg;
      float4 p0 = *reinterpret_cast<const float4*>(&pm[row * 4]);
      gmax[r][reg] = fmaxf(fmaxf(p0.x, p0.y), fmaxf(p0.z, p0.w));
    }
  LDS_BAR()
#pragma unroll
  for (int r = 0; r < 2; ++r)
#pragma unroll
    for (int reg = 0; reg < 4; ++reg) {
      float s = 0.f;
#pragma unroll
      for (int c = 0; c < 4; ++c) {
        acc[r][c][reg] = __expf(acc[r][c][reg] - gmax[r][reg]);
        s += acc[r][c][reg];
      }
#pragma unroll
      for (int msk = 8; msk >= 1; msk >>= 1) s += __shfl_xor(s, msk, 64);
      if (ln15 == 0) pm[(g * 32 + r * 16 + rowq + reg) * 4 + w4] = s;
    }
  LDS_BAR()
#pragma unroll
  for (int r = 0; r < 2; ++r)
#pragma unroll
    for (int reg = 0; reg < 4; ++reg) {
      int row = g * 32 + r * 16 + rowq + reg;
      float4 p0 = *reinterpret_cast<const float4*>(&pm[row * 4]);
      ginv[r][reg] = 1.f / (p0.x + p0.y + p0.z + p0.w);
    }
  LDS_BAR()   // pm fully consumed before P overwrites the region

  // P -> global (for epilogue) and -> P_lds (phase-3 A operand)
  size_t pbase = (size_t)blk * IDF * LL;
#pragma unroll
  for (int r = 0; r < 2; ++r)
#pragma unroll
    for (int c = 0; c < 4; ++c)
#pragma unroll
      for (int reg = 0; reg < 4; ++reg) {
        float p = acc[r][c][reg] * ginv[r][reg];
        int row = g * 32 + r * 16 + rowq + reg;
        int col = w4 * 64 + c * 16 + ln15;
        unsigned short ph = f2h(p);
        P16[pbase + (size_t)row * LL + col] = ph;
        P_lds[row * 256 + ((((col >> 3) ^ (row & 7)) << 3) + (col & 7))] = (short)ph;
      }
  LDS_BAR()

  // ===== Phase 3: N2 = P_lds x ctx[b]^T, K=256 (shared B) =====
#pragma unroll
  for (int r = 0; r < 2; ++r)
#pragma unroll
    for (int c = 0; c < 4; ++c) acc[r][c] = (f32x4){0.f, 0.f, 0.f, 0.f};
  cur = 0;
  {
    const int NSTEP = 8;
#pragma unroll 1
    for (int ks = 0; ks < NSTEP; ++ks) {
      short* Sc = &S[cur * BUFS];
      WAIT_ENTER3(4, 2)
      half8v fa[2], fb[4];
#pragma unroll
      for (int r = 0; r < 2; ++r) {
        int ck = ((ks * 4 + kh) ^ rmask[r]) << 3;
        fa[r] = *reinterpret_cast<const half8v*>(&P_lds[rowM[r] + ck]);
      }
#pragma unroll
      for (int c = 0; c < 4; ++c)
        fb[c] = *reinterpret_cast<const half8v*>(&Sc[offB2[c]]);
      __builtin_amdgcn_s_setprio(1);
#pragma unroll
      for (int r = 0; r < 2; ++r)
#pragma unroll
        for (int c = 0; c < 4; ++c)
          acc[r][c] = __builtin_amdgcn_mfma_f32_16x16x32_f16(fa[r], fb[c], acc[r][c], 0, 0, 0);
      __builtin_amdgcn_s_setprio(0);
      BAR_EXIT()
      if (ks + 3 < NSTEP)
        st_p23(Sc, gC, LL, wave, lane, (ks + 3) * 32);
      cur = (cur == 2) ? 0 : cur + 1;
    }
  }

  size_t nbase = (size_t)b * IDF * KHC + h * CDF;
#pragma unroll
  for (int r = 0; r < 2; ++r)
#pragma unroll
    for (int c = 0; c < 4; ++c)
#pragma unroll
      for (int reg = 0; reg < 4; ++reg) {
        int row = g * 32 + r * 16 + rowq + reg;
        int col = w4 * 64 + c * 16 + ln15;
        N216[nbase + (size_t)row * KHC + col] = f2h(acc[r][c][reg]);
      }
}

// ---------------------------------------------------------------------------
// K4 (MFMA fp16, 3-deep, b-paired): ctx_out[b][i][o] = sum_{hc} N2*W.
// grid 256 = g(2 K-halves) x bp(16) x ot(8). 512 thr = 2 groups (b=bp*2+gr),
// each 4 waves x (64i x 32o). W16 rows staged ONCE for both groups:
// 16 insts/step/block (8 A + 8 B) vs 24 before.
// LDS: 3 x 16KB = 48 KB. Buffer: A_g0 [0,2048) A_g1 [2048,4096) B [4096,8192).
// ---------------------------------------------------------------------------
__device__ __forceinline__ void k4_stage(short* dst,
                                         const short* gA0, const short* gA1,
                                         const short* gW,
                                         int wave, int lane, int kk0, int obase) {
  int h4 = kk0 >> 8, cb = kk0 & 255;
#pragma unroll
  for (int j = 0; j < 2; ++j) {
    int inst = wave * 2 + j;               // 0..15
    if (inst < 8) {                        // A: 2 groups x 4 insts
      int gi = inst >> 2;
      int rb = (inst & 3) * 16;
      int r  = rb + (lane >> 2);           // 0..63
      int gc = (lane & 3) ^ ((r >> 1) & 3);
      const short* src = gi ? gA1 : gA0;
      GLDS16(src + (size_t)r * KHC + kk0 + gc * 8, dst + gi * 2048 + rb * 32);
    } else {                               // B: W rows, shared
      int bi = inst - 8;                   // 0..7
      int brow = bi * 16 + (lane >> 2);    // 0..127
      int gc = (lane & 3) ^ ((brow >> 1) & 3);
      GLDS16(gW + (size_t)(h4 * SSZ + obase + brow) * CDF + cb + gc * 8,
             dst + 4096 + bi * 512);
    }
  }
}

__global__ __launch_bounds__(512) void k4_mfma(const unsigned short* __restrict__ N216,
                                               const unsigned short* __restrict__ W16,
                                               float* __restrict__ out0,
                                               float* __restrict__ out1) {
  __shared__ __align__(16) short S[3 * 8192];   // 48 KB

  int blk = blockIdx.x;
  int g = blk >> 7;
  int r7 = blk & 127;
  int bp = r7 >> 3, ot = r7 & 7;
  int obase = ot * 128;
  int t = threadIdx.x;
  int lane = t & 63, wave = t >> 6;             // 0..7
  int gr = wave >> 2, w4 = wave & 3;            // b-group, wave-in-group
  int ln15 = lane & 15, kh = lane >> 4;

  int b = bp * 2 + gr;
  const short* gA0 = (const short*)N216 + (size_t)(bp * 2 + 0) * IDF * KHC;
  const short* gA1 = (const short*)N216 + (size_t)(bp * 2 + 1) * IDF * KHC;
  const short* gW  = (const short*)W16;

  int offA[4], offB[2];
#pragma unroll
  for (int r = 0; r < 4; ++r) {
    int row = r * 16 + ln15;                   // 0..63
    offA[r] = gr * 2048 + row * 32 + ((kh ^ ((row >> 1) & 3)) * 8);
  }
#pragma unroll
  for (int c = 0; c < 2; ++c) {
    int row = w4 * 32 + c * 16 + ln15;         // 0..127
    offB[c] = 4096 + row * 32 + ((kh ^ ((row >> 1) & 3)) * 8);
  }

  int kbase = g * (KHC / 2);
  f32x4 acc[4][2] = {};

  k4_stage(&S[0],        gA0, gA1, gW, wave, lane, kbase, obase);
  k4_stage(&S[8192],     gA0, gA1, gW, wave, lane, kbase + 32, obase);
  k4_stage(&S[2 * 8192], gA0, gA1, gW, wave, lane, kbase + 64, obase);
  int cur = 0;

  const int NSTEP = 32;
#pragma unroll 1
  for (int ks = 0; ks < NSTEP; ++ks) {
    short* Sc = &S[cur * 8192];
    WAIT_ENTER3(4, 2)
    half8v fa[4], fb[2];
#pragma unroll
    for (int r = 0; r < 4; ++r)
      fa[r] = *reinterpret_cast<const half8v*>(&Sc[offA[r]]);
#pragma unroll
    for (int c = 0; c < 2; ++c)
      fb[c] = *reinterpret_cast<const half8v*>(&Sc[offB[c]]);
    __builtin_amdgcn_s_setprio(1);
#pragma unroll
    for (int r = 0; r < 4; ++r)
#pragma unroll
      for (int c = 0; c < 2; ++c)
        acc[r][c] = __builtin_amdgcn_mfma_f32_16x16x32_f16(fa[r], fb[c], acc[r][c], 0, 0, 0);
    __builtin_amdgcn_s_setprio(0);
    BAR_EXIT()
    if (ks + 3 < NSTEP)
      k4_stage(Sc, gA0, gA1, gW, wave, lane, kbase + (ks + 3) * 32, obase);
    cur = (cur == 2) ? 0 : cur + 1;
  }

  float* dst = (g == 0) ? out0 : out1;
  int rowq = (lane >> 4) * 4;
#pragma unroll
  for (int r = 0; r < 4; ++r)
#pragma unroll
    for (int c = 0; c < 2; ++c)
#pragma unroll
      for (int reg = 0; reg < 4; ++reg)
        dst[((size_t)b * IDF + r * 16 + rowq + reg) * SSZ +
            obase + w4 * 32 + c * 16 + ln15] = acc[r][c][reg];
}

// ---------------------------------------------------------------------------
// Fused epilogue: blocks 0..127 -> attn_out[b][l][i] = sum_h P16[bh][i][l];
// blocks 128..2175 -> out[idx] += Pbuf[idx] (k4 g=1 partial).
// ---------------------------------------------------------------------------
__global__ __launch_bounds__(256) void k_epi(const unsigned short* __restrict__ P16,
                                             float* __restrict__ outa,
                                             float* __restrict__ out,
                                             const float* __restrict__ Pbuf) {
  int blk0 = blockIdx.x;
  int tid = threadIdx.x;
  if (blk0 >= 128) {                       // out += Pbuf
    int idx = (blk0 - 128) * 256 + tid;
    float4 a = reinterpret_cast<float4*>(out)[idx];
    float4 p = reinterpret_cast<const float4*>(Pbuf)[idx];
    a.x += p.x; a.y += p.y; a.z += p.z; a.w += p.w;
    reinterpret_cast<float4*>(out)[idx] = a;
    return;
  }
  __shared__ float T[64][65];
  int b = blk0 >> 2, lt = blk0 & 3;
  int l0 = lt * 64;
  float4 acc[4];
#pragma unroll
  for (int p = 0; p < 4; ++p) acc[p] = make_float4(0.f, 0.f, 0.f, 0.f);
  for (int h = 0; h < NH; ++h) {
    size_t src = (size_t)(b * NH + h) * IDF * LL;
#pragma unroll
    for (int p = 0; p < 4; ++p) {
      int f = tid + p * 256;
      int i = f >> 4, lc = (f & 15) * 4;
      ushort4 u = *reinterpret_cast<const ushort4*>(&P16[src + i * LL + l0 + lc]);
      acc[p].x += h2f(u.x); acc[p].y += h2f(u.y);
      acc[p].z += h2f(u.z); acc[p].w += h2f(u.w);
    }
  }
#pragma unroll
  for (int p = 0; p < 4; ++p) {
    int f = tid + p * 256;
    int i = f >> 4, lc = (f & 15) * 4;
    T[i][lc + 0] = acc[p].x; T[i][lc + 1] = acc[p].y;
    T[i][lc + 2] = acc[p].z; T[i][lc + 3] = acc[p].w;
  }
  __syncthreads();
#pragma unroll
  for (int p = 0; p < 4; ++p) {
    int f = tid + p * 256;
    int lr = f >> 4, ic = (f & 15) * 4;
    float4 v = {T[ic + 0][lr], T[ic + 1][lr], T[ic + 2][lr], T[ic + 3][lr]};
    *reinterpret_cast<float4*>(&outa[((size_t)b * LL + l0 + lr) * IDF + ic]) = v;
  }
}

// ---------------------------------------------------------------------------
extern "C" void kernel_launch(void* const* d_in, const int* in_sizes, int n_in,
                              void* d_out, int out_size, void* d_ws, size_t ws_size,
                              hipStream_t stream) {
  const float* wc  = (const float*)d_in[0];   // [32][64][1024]
  const float* ctx = (const float*)d_in[1];   // [32][256][256]
  const float* W   = (const float*)d_in[2];   // [8][1024][256]
  float* out = (float*)d_out;

  const size_t NE = 2097152;   // elems of wc == W == ctx
  const size_t NM = 4194304;   // elems of P == N2
  unsigned short* p = (unsigned short*)d_ws;
  unsigned short *wc16 = p;   p += NE;
  unsigned short *Wt16 = p;   p += NE;
  unsigned short *W16  = p;   p += NE;
  unsigned short *ctx16 = p;  p += NE;
  unsigned short *cT16 = p;   p += NE;
  unsigned short *P16  = p;   p += NM;
  unsigned short *N216 = p;   p += NM;
  float* Pbuf = (float*)p;    // 2.1M floats

  k_prep  <<<7168, 256, 0, stream>>>(wc, W, ctx, wc16, W16, ctx16, Wt16, cT16);
  k123    <<<256, 512, 0, stream>>>(wc16, Wt16, cT16, ctx16, P16, N216);
  k4_mfma <<<256, 512, 0, stream>>>(N216, W16, out, Pbuf);
  k_epi   <<<2176, 256, 0, stream>>>(P16, out + (size_t)BB * IDF * SSZ, out, Pbuf);
}

// Round 22
// 74.792 us; speedup vs baseline: 1.0997x; 1.0186x over previous
//
#include <hip/hip_runtime.h>
#include <hip/hip_bf16.h>

#define BB 32
#define IDF 64
#define CDF 256
#define SSZ 1024
#define NH 8
#define LL 256
#define KHC 2048   // NH*CDF

typedef __attribute__((ext_vector_type(8))) _Float16 half8v;   // 8 fp16
typedef __attribute__((ext_vector_type(4))) float f32x4;       // MFMA acc

// async global->LDS, 16B per lane, LDS dest = wave-uniform base + lane*16
#define GLDS16(g, l) __builtin_amdgcn_global_load_lds(                        \
    (const __attribute__((address_space(1))) void*)(g),                       \
    (__attribute__((address_space(3))) void*)(l), 16, 0, 0)

// 3-deep pipeline phase entry (T3+T4): wait only for the CURRENT buffer's
// DMA, leaving the next TWO stages in flight. Never vmcnt(0) mid-loop.
#define WAIT_ENTER3(NFULL, NHALF)                                             \
  { if (ks < NSTEP - 2)                                                       \
      asm volatile("s_waitcnt vmcnt(" #NFULL ")" ::: "memory");               \
    else if (ks == NSTEP - 2)                                                 \
      asm volatile("s_waitcnt vmcnt(" #NHALF ")" ::: "memory");               \
    else                                                                      \
      asm volatile("s_waitcnt vmcnt(0)" ::: "memory");                        \
    __builtin_amdgcn_s_barrier();                                             \
    __builtin_amdgcn_sched_barrier(0); }
// phase-1 variant: PER-WAVE vmcnt constants (waves 0-3 issue 3 insts/stage,
// waves 4-7 issue 2) — removes the 4 dup-A instructions/step that existed
// only to keep vmcnt wave-uniform (17% of phase-1 DMA).
#define WAIT_P1()                                                             \
  { if (ks < NSTEP - 2) {                                                     \
      if (wave < 4) asm volatile("s_waitcnt vmcnt(6)" ::: "memory");          \
      else          asm volatile("s_waitcnt vmcnt(4)" ::: "memory");          \
    } else if (ks == NSTEP - 2) {                                             \
      if (wave < 4) asm volatile("s_waitcnt vmcnt(3)" ::: "memory");          \
      else          asm volatile("s_waitcnt vmcnt(2)" ::: "memory");          \
    } else asm volatile("s_waitcnt vmcnt(0)" ::: "memory");                   \
    __builtin_amdgcn_s_barrier();                                             \
    __builtin_amdgcn_sched_barrier(0); }
#define BAR_EXIT()                                                            \
  { __builtin_amdgcn_sched_barrier(0);                                        \
    __builtin_amdgcn_s_barrier();                                             \
    __builtin_amdgcn_sched_barrier(0); }
// LDS-only barrier: drains ds ops but leaves global_load_lds (vmcnt) in
// flight — lets phase-3 prefetch ride through the softmax.
#define LDS_BAR()                                                             \
  { asm volatile("s_waitcnt lgkmcnt(0)" ::: "memory");                        \
    __builtin_amdgcn_s_barrier();                                             \
    __builtin_amdgcn_sched_barrier(0); }

__device__ inline unsigned short f2h(float x) {
  _Float16 h = (_Float16)x;
  return *reinterpret_cast<unsigned short*>(&h);
}
__device__ inline float h2f(unsigned short u) {
  _Float16 h = *reinterpret_cast<_Float16*>(&u);
  return (float)h;
}

// ---------------------------------------------------------------------------
// Fused prep: blocks 0..6143 elementwise casts (wc,W,ctx -> fp16);
// blocks 6144..6655 -> Wt16 [h][c][o]; 6656..7167 -> cT16 [b][l][c].
// ---------------------------------------------------------------------------
__global__ __launch_bounds__(256) void k_prep(const float* __restrict__ wc,
                                              const float* __restrict__ W,
                                              const float* __restrict__ ctx,
                                              unsigned short* __restrict__ wc16,
                                              unsigned short* __restrict__ W16,
                                              unsigned short* __restrict__ ctx16,
                                              unsigned short* __restrict__ Wt16,
                                              unsigned short* __restrict__ cT16) {
  __shared__ float Tt[64][65];
  int blk0 = blockIdx.x;
  int t = threadIdx.x;
  if (blk0 < 6144) {                       // elementwise casts
    int sel = blk0 >> 11;
    int idx = ((blk0 & 2047) * 256 + t) * 4;
    const float* src = (sel == 0) ? wc : (sel == 1) ? W : ctx;
    unsigned short* d = (sel == 0) ? wc16 : (sel == 1) ? W16 : ctx16;
    float4 v = *reinterpret_cast<const float4*>(&src[idx]);
    __align__(8) unsigned short h[4] = {f2h(v.x), f2h(v.y), f2h(v.z), f2h(v.w)};
    *reinterpret_cast<int2*>(&d[idx]) = *reinterpret_cast<int2*>(h);
  } else if (blk0 < 6656) {                // W -> Wt16 [h][c][o]
    int blk = blk0 - 6144;
    int h = blk >> 6, ot = (blk >> 2) & 15, cq = blk & 3;
    int og = ot * 64, cg = cq * 64;
    int o_l = t >> 4, c4 = (t & 15) * 4;
#pragma unroll
    for (int p = 0; p < 4; ++p) {
      int o = o_l + 16 * p;
      float4 v = *reinterpret_cast<const float4*>(
          &W[((size_t)h * SSZ + og + o) * CDF + cg + c4]);
      Tt[c4 + 0][o] = v.x; Tt[c4 + 1][o] = v.y;
      Tt[c4 + 2][o] = v.z; Tt[c4 + 3][o] = v.w;
    }
    __syncthreads();
    int c_l = t >> 2;
#pragma unroll
    for (int p = 0; p < 4; ++p) {
      int o0 = ((t & 3) + 4 * p) * 4;
      __align__(8) unsigned short hv[4];
#pragma unroll
      for (int j = 0; j < 4; ++j) hv[j] = f2h(Tt[c_l][o0 + j]);
      size_t base = ((size_t)h * CDF + cg + c_l) * SSZ + og + o0;
      *reinterpret_cast<int2*>(&Wt16[base]) = *reinterpret_cast<int2*>(hv);
    }
  } else {                                 // ctx -> cT16 [b][l][c]
    int blk = blk0 - 6656;
    int b = blk >> 4, cq = (blk >> 2) & 3, lt = blk & 3;
    int cg = cq * 64, lg = lt * 64;
    int c_l = t >> 4, l4 = (t & 15) * 4;
#pragma unroll
    for (int p = 0; p < 4; ++p) {
      int c = c_l + 16 * p;
      float4 v = *reinterpret_cast<const float4*>(
          &ctx[((size_t)b * CDF + cg + c) * LL + lg + l4]);
      Tt[l4 + 0][c] = v.x; Tt[l4 + 1][c] = v.y;
      Tt[l4 + 2][c] = v.z; Tt[l4 + 3][c] = v.w;
    }
    __syncthreads();
    int l_l = t >> 2;
#pragma unroll
    for (int p = 0; p < 4; ++p) {
      int c0 = ((t & 3) + 4 * p) * 4;
      __align__(8) unsigned short hv[4];
#pragma unroll
      for (int j = 0; j < 4; ++j) hv[j] = f2h(Tt[l_l][c0 + j]);
      size_t base = ((size_t)b * LL + lg + l_l) * CDF + cg + c0;
      *reinterpret_cast<int2*>(&cT16[base]) = *reinterpret_cast<int2*>(hv);
    }
  }
}

// ---------------------------------------------------------------------------
// k123: fused K1+K2+K3, block = (b,h), 512 thr = 8 waves = 2 groups by
// row-half. Phase 1 stages Wt[h] once; phases 2/3 stage cT[b]/ctx[b] once.
// NEW: phase-1 dup-A removed (per-wave vmcnt in WAIT_P1): 20 insts/step.
// LDS: 3 x 20KB staging + 32KB M/P_lds = 92 KB.
// ---------------------------------------------------------------------------
#define BUFS 10240   // shorts per staging buffer (20 KB): A [0,2048) B [2048,10240)

// phase-1 stage, 20 insts: waves 0-3 do {1 A, 2 B}; waves 4-7 do {2 B}.
__device__ __forceinline__ void st_p1(short* dst, const short* gA, const short* gB,
                                      int wave, int lane, int k0) {
  if (wave < 4) {                          // A rows 0..63
    int r = wave * 16 + (lane >> 2);
    int gc = (lane & 3) ^ ((r >> 1) & 3);
    GLDS16(gA + (size_t)r * SSZ + k0 + gc * 8, dst + wave * 512);
  }
#pragma unroll
  for (int j = 0; j < 2; ++j) {            // B rows 0..255
    int bi = wave * 2 + j;                 // 0..15
    int brow = bi * 16 + (lane >> 2);
    int gc = (lane & 3) ^ ((brow >> 1) & 3);
    GLDS16(gB + (size_t)brow * SSZ + k0 + gc * 8, dst + 2048 + bi * 512);
  }
}
// phase-2/3 stage, 16 insts (2/wave): shared B panel 256 rows @ [0,8192).
__device__ __forceinline__ void st_p23(short* dst, const short* gB, int ld,
                                       int wave, int lane, int k0) {
#pragma unroll
  for (int j = 0; j < 2; ++j) {
    int inst = wave * 2 + j;               // 0..15
    int brow = inst * 16 + (lane >> 2);    // 0..255
    int gc = (lane & 3) ^ ((brow >> 1) & 3);
    GLDS16(gB + (size_t)brow * ld + k0 + gc * 8, dst + inst * 512);
  }
}

__global__ __launch_bounds__(512) void k123(const unsigned short* __restrict__ wc16,
                                            const unsigned short* __restrict__ Wt16,
                                            const unsigned short* __restrict__ cT16,
                                            const unsigned short* __restrict__ ctx16,
                                            unsigned short* __restrict__ P16,
                                            unsigned short* __restrict__ N216) {
  __shared__ __align__(16) short S[3 * BUFS + 16384];   // 92 KB
  short* P_lds = &S[3 * BUFS];                           // 64 x 256 fp16

  int blk = blockIdx.x;                    // = bh
  int b = blk >> 3, h = blk & 7;
  int t = threadIdx.x;
  int lane = t & 63, wave = t >> 6;             // 0..7
  int g = wave >> 2, w4 = wave & 3;             // row-half group, wave-in-group
  int ln15 = lane & 15, kh = lane >> 4;
  int rowq = (lane >> 4) * 4;

  const short* gA = (const short*)wc16 + (size_t)b * IDF * SSZ;
  const short* gB = (const short*)Wt16 + (size_t)h * CDF * SSZ;
  const short* gT = (const short*)cT16 + (size_t)b * LL * CDF;
  const short* gC = (const short*)ctx16 + (size_t)b * CDF * LL;

  // A frag offsets: group g's rows = g*32 + r*16 + ln15 (global 0..63)
  int offA[2], rowM[2], rmask[2];
#pragma unroll
  for (int r = 0; r < 2; ++r) {
    int row = g * 32 + r * 16 + ln15;          // 0..63
    offA[r] = row * 32 + ((kh ^ ((row >> 1) & 3)) * 8);
    rowM[r] = row * 256;
    rmask[r] = row & 7;
  }
  // B frag offsets: phase 1 (Wt @2048) and phases 2/3 (shared panel @0)
  int offB1[4], offB2[4];
#pragma unroll
  for (int c = 0; c < 4; ++c) {
    int row = w4 * 64 + c * 16 + ln15;         // 0..255
    int swz = ((kh ^ ((row >> 1) & 3)) * 8);
    offB1[c] = 2048 + row * 32 + swz;
    offB2[c] = row * 32 + swz;
  }

  f32x4 acc[2][4] = {};

  // ===== Phase 1: M = wc x Wt^T, K=1024 =====
  st_p1(&S[0],        gA, gB, wave, lane, 0);
  st_p1(&S[BUFS],     gA, gB, wave, lane, 32);
  st_p1(&S[2 * BUFS], gA, gB, wave, lane, 64);
  int cur = 0;
  {
    const int NSTEP = 32;
#pragma unroll 1
    for (int ks = 0; ks < NSTEP; ++ks) {
      short* Sc = &S[cur * BUFS];
      WAIT_P1()
      half8v fa[2], fb[4];
#pragma unroll
      for (int r = 0; r < 2; ++r)
        fa[r] = *reinterpret_cast<const half8v*>(&Sc[offA[r]]);
#pragma unroll
      for (int c = 0; c < 4; ++c)
        fb[c] = *reinterpret_cast<const half8v*>(&Sc[offB1[c]]);
      __builtin_amdgcn_s_setprio(1);
#pragma unroll
      for (int r = 0; r < 2; ++r)
#pragma unroll
        for (int c = 0; c < 4; ++c)
          acc[r][c] = __builtin_amdgcn_mfma_f32_16x16x32_f16(fa[r], fb[c], acc[r][c], 0, 0, 0);
      __builtin_amdgcn_s_setprio(0);
      BAR_EXIT()
      if (ks + 3 < NSTEP)
        st_p1(Sc, gA, gB, wave, lane, (ks + 3) * 32);
      cur = (cur == 2) ? 0 : cur + 1;
    }
  }
  // M -> P_lds (fp16, chunk-XOR(row&7))
#pragma unroll
  for (int r = 0; r < 2; ++r)
#pragma unroll
    for (int c = 0; c < 4; ++c)
#pragma unroll
      for (int reg = 0; reg < 4; ++reg) {
        int row = g * 32 + r * 16 + rowq + reg;   // 0..63
        int col = w4 * 64 + c * 16 + ln15;        // 0..255
        P_lds[row * 256 + ((((col >> 3) ^ (row & 7)) << 3) + (col & 7))] =
            (short)f2h(acc[r][c][reg]);
      }
  LDS_BAR()

  // ===== Phase 2: logits = M_lds x cT[b]^T, K=256 (shared B) =====
#pragma unroll
  for (int r = 0; r < 2; ++r)
#pragma unroll
    for (int c = 0; c < 4; ++c) acc[r][c] = (f32x4){0.f, 0.f, 0.f, 0.f};
  st_p23(&S[0],        gT, CDF, wave, lane, 0);
  st_p23(&S[BUFS],     gT, CDF, wave, lane, 32);
  st_p23(&S[2 * BUFS], gT, CDF, wave, lane, 64);
  cur = 0;
  {
    const int NSTEP = 8;
#pragma unroll 1
    for (int ks = 0; ks < NSTEP; ++ks) {
      short* Sc = &S[cur * BUFS];
      WAIT_ENTER3(4, 2)
      half8v fa[2], fb[4];
#pragma unroll
      for (int r = 0; r < 2; ++r) {
        int ck = ((ks * 4 + kh) ^ rmask[r]) << 3;
        fa[r] = *reinterpret_cast<const half8v*>(&P_lds[rowM[r] + ck]);
      }
#pragma unroll
      for (int c = 0; c < 4; ++c)
        fb[c] = *reinterpret_cast<const half8v*>(&Sc[offB2[c]]);
      __builtin_amdgcn_s_setprio(1);
#pragma unroll
      for (int r = 0; r < 2; ++r)
#pragma unroll
        for (int c = 0; c < 4; ++c)
          acc[r][c] = __builtin_amdgcn_mfma_f32_16x16x32_f16(fa[r], fb[c], acc[r][c], 0, 0, 0);
      __builtin_amdgcn_s_setprio(0);
      BAR_EXIT()
      if (ks + 3 < NSTEP)
        st_p23(Sc, gT, CDF, wave, lane, (ks + 3) * 32);
      cur = (cur == 2) ? 0 : cur + 1;
    }
  }

  // Prefetch phase-3 B (ctx16) BEFORE softmax; stays in flight (LDS_BAR only).
  st_p23(&S[0],        gC, LL, wave, lane, 0);
  st_p23(&S[BUFS],     gC, LL, wave, lane, 32);
  st_p23(&S[2 * BUFS], gC, LL, wave, lane, 64);

  // ===== Softmax over l (cols). pm overlays first 1 KB of P_lds (M dead). =====
  float* pm = reinterpret_cast<float*>(P_lds);   // 64 rows x 4 floats
  float gmax[2][4], ginv[2][4];
#pragma unroll
  for (int r = 0; r < 2; ++r)
#pragma unroll
    for (int reg = 0; reg < 4; ++reg) {
      float m = fmaxf(fmaxf(acc[r][0][reg], acc[r][1][reg]),
                      fmaxf(acc[r][2][reg], acc[r][3][reg]));
#pragma unroll
      for (int msk = 8; msk >= 1; msk >>= 1) m = fmaxf(m, __shfl_xor(m, msk, 64));
      if (ln15 == 0) pm[(g * 32 + r * 16 + rowq + reg) * 4 + w4] = m;
    }
  LDS_BAR()
#pragma unroll
  for (int r = 0; r < 2; ++r)
#pragma unroll
    for (int reg = 0; reg < 4; ++reg) {
      int row = g * 32 + r * 16 + rowq + reg;
      float4 p0 = *reinterpret_cast<const float4*>(&pm[row * 4]);
      gmax[r][reg] = fmaxf(fmaxf(p0.x, p0.y), fmaxf(p0.z, p0.w));
    }
  LDS_BAR()
#pragma unroll
  for (int r = 0; r < 2; ++r)
#pragma unroll
    for (int reg = 0; reg < 4; ++reg) {
      float s = 0.f;
#pragma unroll
      for (int c = 0; c < 4; ++c) {
        acc[r][c][reg] = __expf(acc[r][c][reg] - gmax[r][reg]);
        s += acc[r][c][reg];
      }
#pragma unroll
      for (int msk = 8; msk >= 1; msk >>= 1) s += __shfl_xor(s, msk, 64);
      if (ln15 == 0) pm[(g * 32 + r * 16 + rowq + reg) * 4 + w4] = s;
    }
  LDS_BAR()
#pragma unroll
  for (int r = 0; r < 2; ++r)
#pragma unroll
    for (int reg = 0; reg < 4; ++reg) {
      int row = g * 32 + r * 16 + rowq + reg;
      float4 p0 = *reinterpret_cast<const float4*>(&pm[row * 4]);
      ginv[r][reg] = 1.f / (p0.x + p0.y + p0.z + p0.w);
    }
  LDS_BAR()   // pm fully consumed before P overwrites the region

  // P -> global (for epilogue) and -> P_lds (phase-3 A operand)
  size_t pbase = (size_t)blk * IDF * LL;
#pragma unroll
  for (int r = 0; r < 2; ++r)
#pragma unroll
    for (int c = 0; c < 4; ++c)
#pragma unroll
      for (int reg = 0; reg < 4; ++reg) {
        float p = acc[r][c][reg] * ginv[r][reg];
        int row = g * 32 + r * 16 + rowq + reg;
        int col = w4 * 64 + c * 16 + ln15;
        unsigned short ph = f2h(p);
        P16[pbase + (size_t)row * LL + col] = ph;
        P_lds[row * 256 + ((((col >> 3) ^ (row & 7)) << 3) + (col & 7))] = (short)ph;
      }
  LDS_BAR()

  // ===== Phase 3: N2 = P_lds x ctx[b]^T, K=256 (shared B) =====
#pragma unroll
  for (int r = 0; r < 2; ++r)
#pragma unroll
    for (int c = 0; c < 4; ++c) acc[r][c] = (f32x4){0.f, 0.f, 0.f, 0.f};
  cur = 0;
  {
    const int NSTEP = 8;
#pragma unroll 1
    for (int ks = 0; ks < NSTEP; ++ks) {
      short* Sc = &S[cur * BUFS];
      WAIT_ENTER3(4, 2)
      half8v fa[2], fb[4];
#pragma unroll
      for (int r = 0; r < 2; ++r) {
        int ck = ((ks * 4 + kh) ^ rmask[r]) << 3;
        fa[r] = *reinterpret_cast<const half8v*>(&P_lds[rowM[r] + ck]);
      }
#pragma unroll
      for (int c = 0; c < 4; ++c)
        fb[c] = *reinterpret_cast<const half8v*>(&Sc[offB2[c]]);
      __builtin_amdgcn_s_setprio(1);
#pragma unroll
      for (int r = 0; r < 2; ++r)
#pragma unroll
        for (int c = 0; c < 4; ++c)
          acc[r][c] = __builtin_amdgcn_mfma_f32_16x16x32_f16(fa[r], fb[c], acc[r][c], 0, 0, 0);
      __builtin_amdgcn_s_setprio(0);
      BAR_EXIT()
      if (ks + 3 < NSTEP)
        st_p23(Sc, gC, LL, wave, lane, (ks + 3) * 32);
      cur = (cur == 2) ? 0 : cur + 1;
    }
  }

  size_t nbase = (size_t)b * IDF * KHC + h * CDF;
#pragma unroll
  for (int r = 0; r < 2; ++r)
#pragma unroll
    for (int c = 0; c < 4; ++c)
#pragma unroll
      for (int reg = 0; reg < 4; ++reg) {
        int row = g * 32 + r * 16 + rowq + reg;
        int col = w4 * 64 + c * 16 + ln15;
        N216[nbase + (size_t)row * KHC + col] = f2h(acc[r][c][reg]);
      }
}

// ---------------------------------------------------------------------------
// K4 (MFMA fp16, 3-deep, b-paired) + P-transpose blocks.
// blocks 0..255: GEMM g(2 K-halves) x bp(16) x ot(8), 2 b-groups of 4 waves.
// blocks 256..383: attn_out transpose (depends only on P16 from k123 —
// runs CONCURRENTLY with the GEMM blocks, removing it from the critical
// path it occupied in the old post-k4 epilogue kernel).
// ---------------------------------------------------------------------------
__device__ __forceinline__ void k4_stage(short* dst,
                                         const short* gA0, const short* gA1,
                                         const short* gW,
                                         int wave, int lane, int kk0, int obase) {
  int h4 = kk0 >> 8, cb = kk0 & 255;
#pragma unroll
  for (int j = 0; j < 2; ++j) {
    int inst = wave * 2 + j;               // 0..15
    if (inst < 8) {                        // A: 2 groups x 4 insts
      int gi = inst >> 2;
      int rb = (inst & 3) * 16;
      int r  = rb + (lane >> 2);           // 0..63
      int gc = (lane & 3) ^ ((r >> 1) & 3);
      const short* src = gi ? gA1 : gA0;
      GLDS16(src + (size_t)r * KHC + kk0 + gc * 8, dst + gi * 2048 + rb * 32);
    } else {                               // B: W rows, shared
      int bi = inst - 8;                   // 0..7
      int brow = bi * 16 + (lane >> 2);    // 0..127
      int gc = (lane & 3) ^ ((brow >> 1) & 3);
      GLDS16(gW + (size_t)(h4 * SSZ + obase + brow) * CDF + cb + gc * 8,
             dst + 4096 + bi * 512);
    }
  }
}

__global__ __launch_bounds__(512) void k4_mfma(const unsigned short* __restrict__ N216,
                                               const unsigned short* __restrict__ W16,
                                               const unsigned short* __restrict__ P16,
                                               float* __restrict__ out0,
                                               float* __restrict__ out1,
                                               float* __restrict__ outa) {
  __shared__ __align__(16) short S[3 * 8192];   // 48 KB

  int blk = blockIdx.x;
  int t = threadIdx.x;

  if (blk >= 256) {
    // ---- P transpose: attn_out[b][l][i] = sum_h P16[bh][i][l], 512 thr ----
    int bblk = blk - 256;
    int b = bblk >> 2, lt = bblk & 3;
    int l0 = lt * 64;
    float* T = reinterpret_cast<float*>(S);    // [64][65] floats (16.6 KB)
    float4 acc2[2];
#pragma unroll
    for (int p = 0; p < 2; ++p) acc2[p] = make_float4(0.f, 0.f, 0.f, 0.f);
    for (int h = 0; h < NH; ++h) {
      size_t src = (size_t)(b * NH + h) * IDF * LL;
#pragma unroll
      for (int p = 0; p < 2; ++p) {
        int f = t + p * 512;
        int i = f >> 4, lc = (f & 15) * 4;
        ushort4 u = *reinterpret_cast<const ushort4*>(&P16[src + i * LL + l0 + lc]);
        acc2[p].x += h2f(u.x); acc2[p].y += h2f(u.y);
        acc2[p].z += h2f(u.z); acc2[p].w += h2f(u.w);
      }
    }
#pragma unroll
    for (int p = 0; p < 2; ++p) {
      int f = t + p * 512;
      int i = f >> 4, lc = (f & 15) * 4;
      T[i * 65 + lc + 0] = acc2[p].x; T[i * 65 + lc + 1] = acc2[p].y;
      T[i * 65 + lc + 2] = acc2[p].z; T[i * 65 + lc + 3] = acc2[p].w;
    }
    __syncthreads();
#pragma unroll
    for (int p = 0; p < 2; ++p) {
      int f = t + p * 512;
      int lr = f >> 4, ic = (f & 15) * 4;
      float4 v = {T[(ic + 0) * 65 + lr], T[(ic + 1) * 65 + lr],
                  T[(ic + 2) * 65 + lr], T[(ic + 3) * 65 + lr]};
      *reinterpret_cast<float4*>(&outa[((size_t)b * LL + l0 + lr) * IDF + ic]) = v;
    }
    return;
  }

  int g = blk >> 7;
  int r7 = blk & 127;
  int bp = r7 >> 3, ot = r7 & 7;
  int obase = ot * 128;
  int lane = t & 63, wave = t >> 6;             // 0..7
  int gr = wave >> 2, w4 = wave & 3;            // b-group, wave-in-group
  int ln15 = lane & 15, kh = lane >> 4;

  int b = bp * 2 + gr;
  const short* gA0 = (const short*)N216 + (size_t)(bp * 2 + 0) * IDF * KHC;
  const short* gA1 = (const short*)N216 + (size_t)(bp * 2 + 1) * IDF * KHC;
  const short* gW  = (const short*)W16;

  int offA[4], offB[2];
#pragma unroll
  for (int r = 0; r < 4; ++r) {
    int row = r * 16 + ln15;                   // 0..63
    offA[r] = gr * 2048 + row * 32 + ((kh ^ ((row >> 1) & 3)) * 8);
  }
#pragma unroll
  for (int c = 0; c < 2; ++c) {
    int row = w4 * 32 + c * 16 + ln15;         // 0..127
    offB[c] = 4096 + row * 32 + ((kh ^ ((row >> 1) & 3)) * 8);
  }

  int kbase = g * (KHC / 2);
  f32x4 acc[4][2] = {};

  k4_stage(&S[0],        gA0, gA1, gW, wave, lane, kbase, obase);
  k4_stage(&S[8192],     gA0, gA1, gW, wave, lane, kbase + 32, obase);
  k4_stage(&S[2 * 8192], gA0, gA1, gW, wave, lane, kbase + 64, obase);
  int cur = 0;

  const int NSTEP = 32;
#pragma unroll 1
  for (int ks = 0; ks < NSTEP; ++ks) {
    short* Sc = &S[cur * 8192];
    WAIT_ENTER3(4, 2)
    half8v fa[4], fb[2];
#pragma unroll
    for (int r = 0; r < 4; ++r)
      fa[r] = *reinterpret_cast<const half8v*>(&Sc[offA[r]]);
#pragma unroll
    for (int c = 0; c < 2; ++c)
      fb[c] = *reinterpret_cast<const half8v*>(&Sc[offB[c]]);
    __builtin_amdgcn_s_setprio(1);
#pragma unroll
    for (int r = 0; r < 4; ++r)
#pragma unroll
      for (int c = 0; c < 2; ++c)
        acc[r][c] = __builtin_amdgcn_mfma_f32_16x16x32_f16(fa[r], fb[c], acc[r][c], 0, 0, 0);
    __builtin_amdgcn_s_setprio(0);
    BAR_EXIT()
    if (ks + 3 < NSTEP)
      k4_stage(Sc, gA0, gA1, gW, wave, lane, kbase + (ks + 3) * 32, obase);
    cur = (cur == 2) ? 0 : cur + 1;
  }

  float* dst = (g == 0) ? out0 : out1;
  int rowq = (lane >> 4) * 4;
#pragma unroll
  for (int r = 0; r < 4; ++r)
#pragma unroll
    for (int c = 0; c < 2; ++c)
#pragma unroll
      for (int reg = 0; reg < 4; ++reg)
        dst[((size_t)b * IDF + r * 16 + rowq + reg) * SSZ +
            obase + w4 * 32 + c * 16 + ln15] = acc[r][c][reg];
}

// ---------------------------------------------------------------------------
// k_add: out[idx] += Pbuf[idx] (fold k4's g=1 K-half partial).
// ---------------------------------------------------------------------------
__global__ __launch_bounds__(256) void k_add(float* __restrict__ out,
                                             const float* __restrict__ Pbuf) {
  int idx = blockIdx.x * 256 + threadIdx.x;
  float4 a = reinterpret_cast<float4*>(out)[idx];
  float4 p = reinterpret_cast<const float4*>(Pbuf)[idx];
  a.x += p.x; a.y += p.y; a.z += p.z; a.w += p.w;
  reinterpret_cast<float4*>(out)[idx] = a;
}

// ---------------------------------------------------------------------------
extern "C" void kernel_launch(void* const* d_in, const int* in_sizes, int n_in,
                              void* d_out, int out_size, void* d_ws, size_t ws_size,
                              hipStream_t stream) {
  const float* wc  = (const float*)d_in[0];   // [32][64][1024]
  const float* ctx = (const float*)d_in[1];   // [32][256][256]
  const float* W   = (const float*)d_in[2];   // [8][1024][256]
  float* out = (float*)d_out;

  const size_t NE = 2097152;   // elems of wc == W == ctx
  const size_t NM = 4194304;   // elems of P == N2
  unsigned short* p = (unsigned short*)d_ws;
  unsigned short *wc16 = p;   p += NE;
  unsigned short *Wt16 = p;   p += NE;
  unsigned short *W16  = p;   p += NE;
  unsigned short *ctx16 = p;  p += NE;
  unsigned short *cT16 = p;   p += NE;
  unsigned short *P16  = p;   p += NM;
  unsigned short *N216 = p;   p += NM;
  float* Pbuf = (float*)p;    // 2.1M floats

  k_prep  <<<7168, 256, 0, stream>>>(wc, W, ctx, wc16, W16, ctx16, Wt16, cT16);
  k123    <<<256, 512, 0, stream>>>(wc16, Wt16, cT16, ctx16, P16, N216);
  k4_mfma <<<384, 512, 0, stream>>>(N216, W16, P16, out, Pbuf,
                                    out + (size_t)BB * IDF * SSZ);
  k_add   <<<2048, 256, 0, stream>>>(out, Pbuf);
}